// Round 2
// baseline (6713.251 us; speedup 1.0000x reference)
//
#include <hip/hip_runtime.h>

typedef unsigned int uint;
typedef unsigned short ushort;

// ---------- bf16 helpers (internal storage only; I/O is fp32) ----------
__device__ __forceinline__ float bflo(uint u) { return __uint_as_float(u << 16); }
__device__ __forceinline__ float bfhi(uint u) { return __uint_as_float(u & 0xffff0000u); }
__device__ __forceinline__ ushort f2bf(float f) {
    uint u = __float_as_uint(f);
    u += 0x7fffu + ((u >> 16) & 1u);   // round-to-nearest-even
    return (ushort)(u >> 16);
}

__device__ __forceinline__ void atomAddF(float* p, float v) {
#if defined(__AMDGCN__) || defined(__HIP_DEVICE_COMPILE__)
    unsafeAtomicAdd(p, v);   // HW global_atomic_add_f32 (no CAS loop)
#else
    atomicAdd(p, v);
#endif
}

#define ND0 200000
#define ND1 100000
#define INF 128
#define HF  256

// ---------- 1) h[n,f] = feat[n,f] * sigmoid(emb[cell_id[n], f]) ; h bf16 ----------
__global__ __launch_bounds__(256) void gate_k(const float* __restrict__ x,
                                              const float* __restrict__ emb,
                                              ushort* __restrict__ h, int total) {
    int idx = blockIdx.x * blockDim.x + threadIdx.x;
    if (idx >= total) return;
    int node = idx >> 7;
    int f    = idx & 127;
    int cell = (int)x[(size_t)node * 129];
    float e  = emb[cell * INF + f];
    float v  = x[(size_t)node * 129 + 1 + f];
    float g  = 1.0f / (1.0f + __expf(-e));
    h[idx] = f2bf(v * g);
}

// ---------- 2) edge scatter: agg[dst,:] += h[src,:], deg[dst] += 1 ----------
template <int F>
__global__ __launch_bounds__(256) void scatter_k(const int* __restrict__ src,
                                                 const int* __restrict__ dst,
                                                 const ushort* __restrict__ h,
                                                 float* __restrict__ agg,
                                                 float* __restrict__ deg, int E) {
    int gtid = blockIdx.x * blockDim.x + threadIdx.x;
    int lane = threadIdx.x & 63;
    int wid  = gtid >> 6;
    int nw   = (gridDim.x * blockDim.x) >> 6;
    for (int e = wid; e < E; e += nw) {
        int s = src[e];
        int d = dst[e];
        const uint* hrow = (const uint*)(h + (size_t)s * F);
        float* arow = agg + (size_t)d * F;
#pragma unroll
        for (int p = 0; p < F / 128; ++p) {
            uint u = hrow[lane + p * 64];
            atomAddF(arow + 2 * (lane + p * 64), bflo(u));
            atomAddF(arow + 2 * (lane + p * 64) + 1, bfhi(u));
        }
        if (lane == 0) atomAddF(deg + d, 1.0f);
    }
}

// ---------- 3) layer1: h1 = relu(h_dst @ Ws + (agg/deg) @ Wn + b1) ; h1 bf16 ----------
// 64-row tile/block, 256 threads = 1 output column each. Rows staged in LDS as
// packed-bf16 pairs: pair index 0..63 = h (k 0..127), 64..127 = agg-mean (k 128..255).
#define TM 64
__global__ __launch_bounds__(256) void layer1_k(const ushort* __restrict__ h,
                                                const float* __restrict__ agg,
                                                const float* __restrict__ deg,
                                                const float* __restrict__ Ws,
                                                const float* __restrict__ Wn,
                                                const float* __restrict__ b1,
                                                ushort* __restrict__ h1, int nrows) {
    __shared__ uint lrow[TM * 128];  // 32 KB
    int t  = threadIdx.x;            // output column in [0,256)
    int r0 = blockIdx.x * TM;
    int nr = min(TM, nrows - r0);

    for (int i = t; i < nr * 64; i += 256) {       // stage h (already bf16)
        int r = i >> 6, f2 = i & 63;
        lrow[r * 128 + f2] = ((const uint*)(h + (size_t)(r0 + r) * 128))[f2];
    }
    for (int i = t; i < nr * 64; i += 256) {       // stage agg-mean, pack to bf16
        int r = i >> 6, f2 = i & 63;
        float inv = 1.0f / fmaxf(deg[r0 + r], 1.0f);
        float a0 = agg[(size_t)(r0 + r) * 128 + 2 * f2] * inv;
        float a1 = agg[(size_t)(r0 + r) * 128 + 2 * f2 + 1] * inv;
        lrow[r * 128 + 64 + f2] = (uint)f2bf(a0) | ((uint)f2bf(a1) << 16);
    }
    __syncthreads();

    float acc[TM];
    float bj = b1[t];
#pragma unroll
    for (int r = 0; r < TM; ++r) acc[r] = bj;

#pragma unroll 1
    for (int k2 = 0; k2 < 128; k2 += 4) {          // k2 = bf16-pair index over K=256
        float w[8];
#pragma unroll
        for (int q = 0; q < 4; ++q) {
            int kp = k2 + q;
            const float* W = (kp < 64) ? Ws : Wn;
            int kk = (2 * kp) & 127;
            w[2 * q]     = W[(size_t)kk * HF + t];
            w[2 * q + 1] = W[(size_t)(kk + 1) * HF + t];
        }
#pragma unroll
        for (int r = 0; r < TM; ++r) {
            uint4 hp = *(const uint4*)&lrow[r * 128 + k2];
            acc[r] += bflo(hp.x) * w[0] + bfhi(hp.x) * w[1]
                    + bflo(hp.y) * w[2] + bfhi(hp.y) * w[3]
                    + bflo(hp.z) * w[4] + bfhi(hp.z) * w[5]
                    + bflo(hp.w) * w[6] + bfhi(hp.w) * w[7];
        }
    }
    for (int r = 0; r < nr; ++r)
        h1[(size_t)(r0 + r) * HF + t] = f2bf(fmaxf(acc[r], 0.0f));
}

// ---------- 4) layer2 head: out = h1_dst @ Ws2 + (agg/deg) @ Wn2 + b2 ----------
// One wave per row; lane handles 4 consecutive k; butterfly-reduce 8 accumulators.
__global__ __launch_bounds__(256) void layer2_k(const ushort* __restrict__ h1,
                                                const float* __restrict__ agg,
                                                const float* __restrict__ deg,
                                                const float* __restrict__ Ws2,
                                                const float* __restrict__ Wn2,
                                                const float* __restrict__ b2,
                                                float* __restrict__ out, int nrows) {
    int gtid = blockIdx.x * blockDim.x + threadIdx.x;
    int lane = threadIdx.x & 63;
    int row  = gtid >> 6;
    if (row >= nrows) return;

    float inv = 1.0f / fmaxf(deg[row], 1.0f);
    // lane covers k = 4*lane .. 4*lane+3
    uint2  hp = *(const uint2*)(h1 + (size_t)row * HF + 4 * lane);      // 4 bf16
    float4 ap = *(const float4*)(agg + (size_t)row * HF + 4 * lane);    // 4 fp32
    float hv[4] = { bflo(hp.x), bfhi(hp.x), bflo(hp.y), bfhi(hp.y) };
    float av[4] = { ap.x * inv, ap.y * inv, ap.z * inv, ap.w * inv };

    float acc[8];
#pragma unroll
    for (int c = 0; c < 8; ++c) acc[c] = 0.0f;
#pragma unroll
    for (int q = 0; q < 4; ++q) {
        int k = 4 * lane + q;
        const float4* ws = (const float4*)(Ws2 + k * 8);
        const float4* wn = (const float4*)(Wn2 + k * 8);
        float4 s0 = ws[0], s1 = ws[1], n0 = wn[0], n1 = wn[1];
        acc[0] += hv[q] * s0.x + av[q] * n0.x;
        acc[1] += hv[q] * s0.y + av[q] * n0.y;
        acc[2] += hv[q] * s0.z + av[q] * n0.z;
        acc[3] += hv[q] * s0.w + av[q] * n0.w;
        acc[4] += hv[q] * s1.x + av[q] * n1.x;
        acc[5] += hv[q] * s1.y + av[q] * n1.y;
        acc[6] += hv[q] * s1.z + av[q] * n1.z;
        acc[7] += hv[q] * s1.w + av[q] * n1.w;
    }
#pragma unroll
    for (int off = 32; off > 0; off >>= 1)
#pragma unroll
        for (int c = 0; c < 8; ++c) acc[c] += __shfl_down(acc[c], off, 64);

    if (lane == 0) {
        float4 o0 = { acc[0] + b2[0], acc[1] + b2[1], acc[2] + b2[2], acc[3] + b2[3] };
        float4 o1 = { acc[4] + b2[4], acc[5] + b2[5], acc[6] + b2[6], acc[7] + b2[7] };
        *(float4*)(out + (size_t)row * 8)     = o0;
        *(float4*)(out + (size_t)row * 8 + 4) = o1;
    }
}

extern "C" void kernel_launch(void* const* d_in, const int* in_sizes, int n_in,
                              void* d_out, int out_size, void* d_ws, size_t ws_size,
                              hipStream_t stream) {
    const float* x    = (const float*)d_in[0];
    const int*   src0 = (const int*)d_in[1];
    const int*   dst0 = (const int*)d_in[2];
    const int*   src1 = (const int*)d_in[3];
    const int*   dst1 = (const int*)d_in[4];
    const float* emb  = (const float*)d_in[7];
    const float* Ws1  = (const float*)d_in[8];
    const float* Wn1  = (const float*)d_in[9];
    const float* b1   = (const float*)d_in[10];
    const float* Ws2  = (const float*)d_in[11];
    const float* Wn2  = (const float*)d_in[12];
    const float* b2   = (const float*)d_in[13];
    int E0 = in_sizes[1];
    int E1 = in_sizes[3];
    int nsrc = in_sizes[0] / 129;   // 400000

    // workspace layout (floats): agg[25.6M] | deg[200k] | h bf16[51.2M sh] | h1 bf16[51.2M sh]
    const size_t AGG_ELEMS = (size_t)ND0 * INF;   // == ND1 * HF
    float*  agg = (float*)d_ws;
    float*  deg = agg + AGG_ELEMS;
    ushort* h   = (ushort*)(deg + ND0);
    ushort* h1  = h + (size_t)nsrc * INF;

    int total0 = nsrc * INF;
    hipMemsetAsync(d_ws, 0, (AGG_ELEMS + ND0) * sizeof(float), stream);
    gate_k<<<(total0 + 255) / 256, 256, 0, stream>>>(x, emb, h, total0);

    scatter_k<128><<<2048, 256, 0, stream>>>(src0, dst0, h, agg, deg, E0);
    layer1_k<<<(ND0 + TM - 1) / TM, 256, 0, stream>>>(h, agg, deg, Ws1, Wn1, b1, h1, ND0);

    hipMemsetAsync(d_ws, 0, (AGG_ELEMS + ND0) * sizeof(float), stream);
    scatter_k<256><<<2048, 256, 0, stream>>>(src1, dst1, h1, agg, deg, E1);
    layer2_k<<<(ND1 + 3) / 4, 256, 0, stream>>>(h1, agg, deg, Ws2, Wn2, b2,
                                                (float*)d_out, ND1);
}

// Round 3
// 2169.924 us; speedup vs baseline: 3.0938x; 3.0938x over previous
//
#include <hip/hip_runtime.h>

typedef unsigned int uint;
typedef unsigned short ushort;

// ---------- bf16 helpers (internal storage only; I/O is fp32) ----------
__device__ __forceinline__ float bflo(uint u) { return __uint_as_float(u << 16); }
__device__ __forceinline__ float bfhi(uint u) { return __uint_as_float(u & 0xffff0000u); }
__device__ __forceinline__ ushort f2bf(float f) {
    uint u = __float_as_uint(f);
    u += 0x7fffu + ((u >> 16) & 1u);   // round-to-nearest-even
    return (ushort)(u >> 16);
}
__device__ __forceinline__ uint pack2(float a, float b) {
    return (uint)f2bf(a) | ((uint)f2bf(b) << 16);
}

#define ND0 200000
#define ND1 100000
#define INF 128
#define HF  256

// ---------- 1) gate: h[n,f] = feat * sigmoid(emb[cell_id]) ; h bf16 ----------
__global__ __launch_bounds__(256) void gate_k(const float* __restrict__ x,
                                              const float* __restrict__ emb,
                                              ushort* __restrict__ h, int total) {
    int idx = blockIdx.x * blockDim.x + threadIdx.x;
    if (idx >= total) return;
    int node = idx >> 7;
    int f    = idx & 127;
    int cell = (int)x[(size_t)node * 129];
    float e  = emb[cell * INF + f];
    float v  = x[(size_t)node * 129 + 1 + f];
    float g  = 1.0f / (1.0f + __expf(-e));
    h[idx] = f2bf(v * g);
}

// ---------- CSR build: histogram -> scan -> placement ----------
__global__ __launch_bounds__(256) void hist_k(const int* __restrict__ dst,
                                              int* __restrict__ cnt, int E) {
    int i = blockIdx.x * blockDim.x + threadIdx.x;
    if (i < E) atomicAdd(&cnt[dst[i]], 1);
}

#define SCAN_B 1024
__global__ __launch_bounds__(256) void scan1_k(const int* __restrict__ in,
                                               int* __restrict__ out,
                                               int* __restrict__ bsum, int n) {
    __shared__ int tmp[256];
    int t = threadIdx.x;
    int base = blockIdx.x * SCAN_B;
    int v[4], s = 0;
#pragma unroll
    for (int q = 0; q < 4; ++q) {
        int idx = base + t * 4 + q;
        v[q] = (idx < n) ? in[idx] : 0;
        s += v[q];
    }
    tmp[t] = s; __syncthreads();
    for (int off = 1; off < 256; off <<= 1) {
        int xv = (t >= off) ? tmp[t - off] : 0; __syncthreads();
        tmp[t] += xv; __syncthreads();
    }
    int excl = tmp[t] - s;
#pragma unroll
    for (int q = 0; q < 4; ++q) {
        int idx = base + t * 4 + q;
        if (idx < n) out[idx] = excl;
        excl += v[q];
    }
    if (t == 255) bsum[blockIdx.x] = tmp[255];
}

__global__ __launch_bounds__(256) void scan2_k(int* __restrict__ bsum, int nb) {
    __shared__ int tmp[256];
    int t = threadIdx.x;
    int s = (t < nb) ? bsum[t] : 0;
    tmp[t] = s; __syncthreads();
    for (int off = 1; off < 256; off <<= 1) {
        int xv = (t >= off) ? tmp[t - off] : 0; __syncthreads();
        tmp[t] += xv; __syncthreads();
    }
    if (t < nb) bsum[t] = tmp[t] - s;   // exclusive
}

__global__ __launch_bounds__(256) void scan3_k(int* __restrict__ row_start,
                                               int* __restrict__ cursor,
                                               const int* __restrict__ bsum, int n) {
    int i = blockIdx.x * blockDim.x + threadIdx.x;
    if (i < n) {
        int v = row_start[i] + bsum[i >> 10];
        row_start[i] = v;
        cursor[i]    = v;
    }
}

__global__ __launch_bounds__(256) void place_k(const int* __restrict__ src,
                                               const int* __restrict__ dst,
                                               int* __restrict__ cursor,
                                               int* __restrict__ csr, int E) {
    int i = blockIdx.x * blockDim.x + threadIdx.x;
    if (i < E) {
        int p = atomicAdd(&cursor[dst[i]], 1);
        csr[p] = src[i];
    }
}

// ---------- gather-aggregate: one wave per dst row, mean in registers ----------
// FU = uints per row (F/2): 64 for F=128, 128 for F=256. Output packed bf16 mean.
template <int FU>
__global__ __launch_bounds__(256) void gather_k(const int* __restrict__ csr,
                                                const int* __restrict__ row_start,
                                                const int* __restrict__ cnt,
                                                const ushort* __restrict__ hsrc,
                                                uint* __restrict__ aggm, int nrows) {
    int w    = (blockIdx.x * blockDim.x + threadIdx.x) >> 6;
    int lane = threadIdx.x & 63;
    if (w >= nrows) return;
    int beg = row_start[w], c = cnt[w], end = beg + c;
    const uint* hb = (const uint*)hsrc;
    float a0 = 0.f, a1 = 0.f, a2 = 0.f, a3 = 0.f;
    int j = beg;
    for (; j + 1 < end; j += 2) {
        int s0 = csr[j], s1 = csr[j + 1];
        if (FU == 64) {
            uint u0 = hb[(size_t)s0 * 64 + lane];
            uint u1 = hb[(size_t)s1 * 64 + lane];
            a0 += bflo(u0) + bflo(u1);
            a1 += bfhi(u0) + bfhi(u1);
        } else {
            uint2 u0 = *(const uint2*)(hb + (size_t)s0 * 128 + 2 * lane);
            uint2 u1 = *(const uint2*)(hb + (size_t)s1 * 128 + 2 * lane);
            a0 += bflo(u0.x) + bflo(u1.x);
            a1 += bfhi(u0.x) + bfhi(u1.x);
            a2 += bflo(u0.y) + bflo(u1.y);
            a3 += bfhi(u0.y) + bfhi(u1.y);
        }
    }
    if (j < end) {
        int s0 = csr[j];
        if (FU == 64) {
            uint u0 = hb[(size_t)s0 * 64 + lane];
            a0 += bflo(u0); a1 += bfhi(u0);
        } else {
            uint2 u0 = *(const uint2*)(hb + (size_t)s0 * 128 + 2 * lane);
            a0 += bflo(u0.x); a1 += bfhi(u0.x);
            a2 += bflo(u0.y); a3 += bfhi(u0.y);
        }
    }
    float inv = 1.0f / fmaxf((float)c, 1.0f);
    if (FU == 64) {
        aggm[(size_t)w * 64 + lane] = pack2(a0 * inv, a1 * inv);
    } else {
        uint2 o;
        o.x = pack2(a0 * inv, a1 * inv);
        o.y = pack2(a2 * inv, a3 * inv);
        *(uint2*)(aggm + (size_t)w * 128 + 2 * lane) = o;
    }
}

// ---------- layer1: h1 = relu(h_dst @ Ws + aggm @ Wn + b1) ; h1 bf16 ----------
// 64-row tile/block, 256 threads = 1 output column each. Rows staged in LDS as
// packed-bf16 pairs: uint 0..63 = h row (k 0..127), 64..127 = aggm row (k 128..255).
#define TM 64
__global__ __launch_bounds__(256) void layer1_k(const ushort* __restrict__ h,
                                                const uint* __restrict__ aggm,
                                                const float* __restrict__ Ws,
                                                const float* __restrict__ Wn,
                                                const float* __restrict__ b1,
                                                ushort* __restrict__ h1, int nrows) {
    __shared__ uint lrow[TM * 128];  // 32 KB
    int t  = threadIdx.x;
    int r0 = blockIdx.x * TM;
    int nr = min(TM, nrows - r0);

    for (int i = t; i < nr * 64; i += 256) {
        int r = i >> 6, f2 = i & 63;
        lrow[r * 128 + f2]      = ((const uint*)(h + (size_t)(r0 + r) * 128))[f2];
        lrow[r * 128 + 64 + f2] = aggm[(size_t)(r0 + r) * 64 + f2];
    }
    __syncthreads();

    float acc[TM];
    float bj = b1[t];
#pragma unroll
    for (int r = 0; r < TM; ++r) acc[r] = bj;

#pragma unroll 1
    for (int k2 = 0; k2 < 128; k2 += 4) {
        float w[8];
#pragma unroll
        for (int q = 0; q < 4; ++q) {
            int kp = k2 + q;
            const float* W = (kp < 64) ? Ws : Wn;
            int kk = (2 * kp) & 127;
            w[2 * q]     = W[(size_t)kk * HF + t];
            w[2 * q + 1] = W[(size_t)(kk + 1) * HF + t];
        }
#pragma unroll
        for (int r = 0; r < TM; ++r) {
            uint4 hp = *(const uint4*)&lrow[r * 128 + k2];
            acc[r] += bflo(hp.x) * w[0] + bfhi(hp.x) * w[1]
                    + bflo(hp.y) * w[2] + bfhi(hp.y) * w[3]
                    + bflo(hp.z) * w[4] + bfhi(hp.z) * w[5]
                    + bflo(hp.w) * w[6] + bfhi(hp.w) * w[7];
        }
    }
    for (int r = 0; r < nr; ++r)
        h1[(size_t)(r0 + r) * HF + t] = f2bf(fmaxf(acc[r], 0.0f));
}

// ---------- layer2 head: out = h1_dst @ Ws2 + aggm1 @ Wn2 + b2 ----------
__global__ __launch_bounds__(256) void layer2_k(const ushort* __restrict__ h1,
                                                const uint* __restrict__ aggm,
                                                const float* __restrict__ Ws2,
                                                const float* __restrict__ Wn2,
                                                const float* __restrict__ b2,
                                                float* __restrict__ out, int nrows) {
    int gtid = blockIdx.x * blockDim.x + threadIdx.x;
    int lane = threadIdx.x & 63;
    int row  = gtid >> 6;
    if (row >= nrows) return;

    uint2 hp = *(const uint2*)(h1 + (size_t)row * HF + 4 * lane);
    uint2 ap = *(const uint2*)(aggm + (size_t)row * 128 + 2 * lane);
    float hv[4] = { bflo(hp.x), bfhi(hp.x), bflo(hp.y), bfhi(hp.y) };
    float av[4] = { bflo(ap.x), bfhi(ap.x), bflo(ap.y), bfhi(ap.y) };

    float acc[8];
#pragma unroll
    for (int c = 0; c < 8; ++c) acc[c] = 0.0f;
#pragma unroll
    for (int q = 0; q < 4; ++q) {
        int k = 4 * lane + q;
        const float4* ws = (const float4*)(Ws2 + k * 8);
        const float4* wn = (const float4*)(Wn2 + k * 8);
        float4 s0 = ws[0], s1 = ws[1], n0 = wn[0], n1 = wn[1];
        acc[0] += hv[q] * s0.x + av[q] * n0.x;
        acc[1] += hv[q] * s0.y + av[q] * n0.y;
        acc[2] += hv[q] * s0.z + av[q] * n0.z;
        acc[3] += hv[q] * s0.w + av[q] * n0.w;
        acc[4] += hv[q] * s1.x + av[q] * n1.x;
        acc[5] += hv[q] * s1.y + av[q] * n1.y;
        acc[6] += hv[q] * s1.z + av[q] * n1.z;
        acc[7] += hv[q] * s1.w + av[q] * n1.w;
    }
#pragma unroll
    for (int off = 32; off > 0; off >>= 1)
#pragma unroll
        for (int c = 0; c < 8; ++c) acc[c] += __shfl_down(acc[c], off, 64);

    if (lane == 0) {
        float4 o0 = { acc[0] + b2[0], acc[1] + b2[1], acc[2] + b2[2], acc[3] + b2[3] };
        float4 o1 = { acc[4] + b2[4], acc[5] + b2[5], acc[6] + b2[6], acc[7] + b2[7] };
        *(float4*)(out + (size_t)row * 8)     = o0;
        *(float4*)(out + (size_t)row * 8 + 4) = o1;
    }
}

extern "C" void kernel_launch(void* const* d_in, const int* in_sizes, int n_in,
                              void* d_out, int out_size, void* d_ws, size_t ws_size,
                              hipStream_t stream) {
    const float* x    = (const float*)d_in[0];
    const int*   src0 = (const int*)d_in[1];
    const int*   dst0 = (const int*)d_in[2];
    const int*   src1 = (const int*)d_in[3];
    const int*   dst1 = (const int*)d_in[4];
    const float* emb  = (const float*)d_in[7];
    const float* Ws1  = (const float*)d_in[8];
    const float* Wn1  = (const float*)d_in[9];
    const float* b1   = (const float*)d_in[10];
    const float* Ws2  = (const float*)d_in[11];
    const float* Wn2  = (const float*)d_in[12];
    const float* b2   = (const float*)d_in[13];
    int E0 = in_sizes[1];
    int E1 = in_sizes[3];
    int nsrc = in_sizes[0] / 129;   // 400000

    // ---- workspace layout (~272 MB) ----
    char* p = (char*)d_ws;
    ushort* h         = (ushort*)p;  p += (size_t)nsrc * INF * 2;   // 102.4 MB
    ushort* h1        = (ushort*)p;  p += (size_t)ND0 * HF * 2;     // 102.4 MB
    uint*   aggm      = (uint*)p;    p += (size_t)ND0 * 64 * 4;     // 51.2 MB (reused L1)
    int*    csr       = (int*)p;     p += (size_t)E0 * 4;           // 12.8 MB (reused L1)
    int*    cnt       = (int*)p;     p += (size_t)ND0 * 4;
    int*    row_start = (int*)p;     p += (size_t)ND0 * 4;
    int*    cursor    = (int*)p;     p += (size_t)ND0 * 4;
    int*    bsum      = (int*)p;     p += 256 * 4;

    int total0 = nsrc * INF;

    // ---- layer 0/1 ----
    hipMemsetAsync(cnt, 0, (size_t)ND0 * 4, stream);
    gate_k<<<(total0 + 255) / 256, 256, 0, stream>>>(x, emb, h, total0);
    hist_k<<<(E0 + 255) / 256, 256, 0, stream>>>(dst0, cnt, E0);
    int nb0 = (ND0 + SCAN_B - 1) / SCAN_B;   // 196
    scan1_k<<<nb0, 256, 0, stream>>>(cnt, row_start, bsum, ND0);
    scan2_k<<<1, 256, 0, stream>>>(bsum, nb0);
    scan3_k<<<(ND0 + 255) / 256, 256, 0, stream>>>(row_start, cursor, bsum, ND0);
    place_k<<<(E0 + 255) / 256, 256, 0, stream>>>(src0, dst0, cursor, csr, E0);
    gather_k<64><<<(ND0 + 3) / 4, 256, 0, stream>>>(csr, row_start, cnt, h, aggm, ND0);
    layer1_k<<<(ND0 + TM - 1) / TM, 256, 0, stream>>>(h, aggm, Ws1, Wn1, b1, h1, ND0);

    // ---- layer 2 ----
    hipMemsetAsync(cnt, 0, (size_t)ND1 * 4, stream);
    hist_k<<<(E1 + 255) / 256, 256, 0, stream>>>(dst1, cnt, E1);
    int nb1 = (ND1 + SCAN_B - 1) / SCAN_B;   // 98
    scan1_k<<<nb1, 256, 0, stream>>>(cnt, row_start, bsum, ND1);
    scan2_k<<<1, 256, 0, stream>>>(bsum, nb1);
    scan3_k<<<(ND1 + 255) / 256, 256, 0, stream>>>(row_start, cursor, bsum, ND1);
    place_k<<<(E1 + 255) / 256, 256, 0, stream>>>(src1, dst1, cursor, csr, E1);
    gather_k<128><<<(ND1 + 3) / 4, 256, 0, stream>>>(csr, row_start, cnt, h1, aggm, ND1);
    layer2_k<<<(ND1 + 3) / 4, 256, 0, stream>>>(h1, aggm, Ws2, Wn2, b2,
                                                (float*)d_out, ND1);
}

// Round 4
// 1565.013 us; speedup vs baseline: 4.2896x; 1.3865x over previous
//
#include <hip/hip_runtime.h>

typedef unsigned int uint;
typedef unsigned short ushort;
typedef __attribute__((ext_vector_type(8))) short short8;   // 8 bf16 (4 VGPRs)
typedef __attribute__((ext_vector_type(4))) float f32x4;    // MFMA accumulator

// ---------- bf16 helpers (internal storage only; I/O is fp32) ----------
__device__ __forceinline__ float bflo(uint u) { return __uint_as_float(u << 16); }
__device__ __forceinline__ float bfhi(uint u) { return __uint_as_float(u & 0xffff0000u); }
__device__ __forceinline__ ushort f2bf(float f) {
    uint u = __float_as_uint(f);
    u += 0x7fffu + ((u >> 16) & 1u);   // round-to-nearest-even
    return (ushort)(u >> 16);
}
__device__ __forceinline__ uint pack2(float a, float b) {
    return (uint)f2bf(a) | ((uint)f2bf(b) << 16);
}

#define ND0 200000
#define ND1 100000
#define INF 128
#define HF  256

// ---------- 1) gate: h[n,f] = feat * sigmoid(emb[cell_id]) ; h bf16 ----------
__global__ __launch_bounds__(256) void gate_k(const float* __restrict__ x,
                                              const float* __restrict__ emb,
                                              ushort* __restrict__ h, int total) {
    int idx = blockIdx.x * blockDim.x + threadIdx.x;
    if (idx >= total) return;
    int node = idx >> 7;
    int f    = idx & 127;
    int cell = (int)x[(size_t)node * 129];
    float e  = emb[cell * INF + f];
    float v  = x[(size_t)node * 129 + 1 + f];
    float g  = 1.0f / (1.0f + __expf(-e));
    h[idx] = f2bf(v * g);
}

// ---------- CSR build: histogram -> scan -> placement ----------
__global__ __launch_bounds__(256) void hist_k(const int* __restrict__ dst,
                                              int* __restrict__ cnt, int E) {
    int i = blockIdx.x * blockDim.x + threadIdx.x;
    if (i < E) atomicAdd(&cnt[dst[i]], 1);
}

#define SCAN_B 1024
__global__ __launch_bounds__(256) void scan1_k(const int* __restrict__ in,
                                               int* __restrict__ out,
                                               int* __restrict__ bsum, int n) {
    __shared__ int tmp[256];
    int t = threadIdx.x;
    int base = blockIdx.x * SCAN_B;
    int v[4], s = 0;
#pragma unroll
    for (int q = 0; q < 4; ++q) {
        int idx = base + t * 4 + q;
        v[q] = (idx < n) ? in[idx] : 0;
        s += v[q];
    }
    tmp[t] = s; __syncthreads();
    for (int off = 1; off < 256; off <<= 1) {
        int xv = (t >= off) ? tmp[t - off] : 0; __syncthreads();
        tmp[t] += xv; __syncthreads();
    }
    int excl = tmp[t] - s;
#pragma unroll
    for (int q = 0; q < 4; ++q) {
        int idx = base + t * 4 + q;
        if (idx < n) out[idx] = excl;
        excl += v[q];
    }
    if (t == 255) bsum[blockIdx.x] = tmp[255];
}

__global__ __launch_bounds__(256) void scan2_k(int* __restrict__ bsum, int nb) {
    __shared__ int tmp[256];
    int t = threadIdx.x;
    int s = (t < nb) ? bsum[t] : 0;
    tmp[t] = s; __syncthreads();
    for (int off = 1; off < 256; off <<= 1) {
        int xv = (t >= off) ? tmp[t - off] : 0; __syncthreads();
        tmp[t] += xv; __syncthreads();
    }
    if (t < nb) bsum[t] = tmp[t] - s;   // exclusive
}

__global__ __launch_bounds__(256) void scan3_k(int* __restrict__ row_start,
                                               int* __restrict__ cursor,
                                               const int* __restrict__ bsum, int n) {
    int i = blockIdx.x * blockDim.x + threadIdx.x;
    if (i < n) {
        int v = row_start[i] + bsum[i >> 10];
        row_start[i] = v;
        cursor[i]    = v;
    }
}

__global__ __launch_bounds__(256) void place_k(const int* __restrict__ src,
                                               const int* __restrict__ dst,
                                               int* __restrict__ cursor,
                                               int* __restrict__ csr, int E) {
    int i = blockIdx.x * blockDim.x + threadIdx.x;
    if (i < E) {
        int p = atomicAdd(&cursor[dst[i]], 1);
        csr[p] = src[i];
    }
}

// ---------- gather-aggregate: one wave per dst row, mean in registers ----------
template <int FU>
__global__ __launch_bounds__(256) void gather_k(const int* __restrict__ csr,
                                                const int* __restrict__ row_start,
                                                const int* __restrict__ cnt,
                                                const ushort* __restrict__ hsrc,
                                                uint* __restrict__ aggm, int nrows) {
    int w    = (blockIdx.x * blockDim.x + threadIdx.x) >> 6;
    int lane = threadIdx.x & 63;
    if (w >= nrows) return;
    int beg = row_start[w], c = cnt[w], end = beg + c;
    const uint* hb = (const uint*)hsrc;
    float a0 = 0.f, a1 = 0.f, a2 = 0.f, a3 = 0.f;
    int j = beg;
    for (; j + 1 < end; j += 2) {
        int s0 = csr[j], s1 = csr[j + 1];
        if (FU == 64) {
            uint u0 = hb[(size_t)s0 * 64 + lane];
            uint u1 = hb[(size_t)s1 * 64 + lane];
            a0 += bflo(u0) + bflo(u1);
            a1 += bfhi(u0) + bfhi(u1);
        } else {
            uint2 u0 = *(const uint2*)(hb + (size_t)s0 * 128 + 2 * lane);
            uint2 u1 = *(const uint2*)(hb + (size_t)s1 * 128 + 2 * lane);
            a0 += bflo(u0.x) + bflo(u1.x);
            a1 += bfhi(u0.x) + bfhi(u1.x);
            a2 += bflo(u0.y) + bflo(u1.y);
            a3 += bfhi(u0.y) + bfhi(u1.y);
        }
    }
    if (j < end) {
        int s0 = csr[j];
        if (FU == 64) {
            uint u0 = hb[(size_t)s0 * 64 + lane];
            a0 += bflo(u0); a1 += bfhi(u0);
        } else {
            uint2 u0 = *(const uint2*)(hb + (size_t)s0 * 128 + 2 * lane);
            a0 += bflo(u0.x); a1 += bfhi(u0.x);
            a2 += bflo(u0.y); a3 += bfhi(u0.y);
        }
    }
    float inv = 1.0f / fmaxf((float)c, 1.0f);
    if (FU == 64) {
        aggm[(size_t)w * 64 + lane] = pack2(a0 * inv, a1 * inv);
    } else {
        uint2 o;
        o.x = pack2(a0 * inv, a1 * inv);
        o.y = pack2(a2 * inv, a3 * inv);
        *(uint2*)(aggm + (size_t)w * 128 + 2 * lane) = o;
    }
}

// ---------- W pack: [Ws1;Wn1] (256x256 f32) -> B-fragment-major bf16 ----------
// Frag (ks,nf): lane holds B[k=ks*32+quad*8+j][n=nf*16+(lane&15)], j=0..7 -> one uint4.
__global__ __launch_bounds__(256) void wconv_k(const float* __restrict__ Ws,
                                               const float* __restrict__ Wn,
                                               uint* __restrict__ Wb) {
    int tid  = blockIdx.x * 256 + threadIdx.x;   // 8192 threads
    int lane = tid & 63, nf = (tid >> 6) & 15, ks = tid >> 10;
    int n  = nf * 16 + (lane & 15);
    int k0 = ks * 32 + ((lane >> 4) << 3);
    uint o[4];
#pragma unroll
    for (int p = 0; p < 4; ++p) {
        int k = k0 + 2 * p;
        float a = (k < 128)     ? Ws[(size_t)k * HF + n]       : Wn[(size_t)(k - 128) * HF + n];
        float b = (k + 1 < 128) ? Ws[(size_t)(k + 1) * HF + n] : Wn[(size_t)(k - 127) * HF + n];
        o[p] = pack2(a, b);
    }
    uint4 v = { o[0], o[1], o[2], o[3] };
    *(uint4*)(Wb + (size_t)tid * 4) = v;
}

// ---------- layer1 MFMA: h1 = relu([h|aggm] @ Wb + b1), 64x256 tile/block ----------
__global__ __launch_bounds__(256) void layer1_mfma_k(const uint* __restrict__ hb,
                                                     const uint* __restrict__ aggm,
                                                     const uint* __restrict__ Wb,
                                                     const float* __restrict__ b1,
                                                     uint* __restrict__ h1u, int nrows) {
    __shared__ uint lds[64 * 132];   // 33792 B; X tile (stride 132 dwords) / out tile
    int t = threadIdx.x, lane = t & 63, wid = t >> 6;
    int quad = lane >> 4, l16 = lane & 15;
    int r0 = blockIdx.x * 64;

    // stage X = [h(64 uints) | aggm(64 uints)] per row, uint4 loads
#pragma unroll
    for (int it = 0; it < 8; ++it) {
        int i = t + it * 256;
        int r = i >> 5, u4 = i & 31;
        const uint* src = (u4 < 16) ? (hb + (size_t)(r0 + r) * 64 + u4 * 4)
                                    : (aggm + (size_t)(r0 + r) * 64 + (u4 - 16) * 4);
        *(uint4*)&lds[r * 132 + u4 * 4] = *(const uint4*)src;
    }

    float bias[4];
#pragma unroll
    for (int i = 0; i < 4; ++i) bias[i] = b1[wid * 64 + i * 16 + l16];
    f32x4 acc[4][4];
#pragma unroll
    for (int mf = 0; mf < 4; ++mf)
#pragma unroll
        for (int i = 0; i < 4; ++i)
            acc[mf][i] = (f32x4){ bias[i], bias[i], bias[i], bias[i] };

    __syncthreads();

#pragma unroll
    for (int ks = 0; ks < 8; ++ks) {
        short8 bfr[4];
#pragma unroll
        for (int i = 0; i < 4; ++i) {
            int nf = wid * 4 + i;
            bfr[i] = *(const short8*)(Wb + (size_t)((ks * 16 + nf) * 64 + lane) * 4);
        }
        short8 afr[4];
#pragma unroll
        for (int mf = 0; mf < 4; ++mf) {
            int r = mf * 16 + l16;
            afr[mf] = *(const short8*)&lds[r * 132 + ks * 16 + quad * 4];
        }
#pragma unroll
        for (int mf = 0; mf < 4; ++mf)
#pragma unroll
            for (int i = 0; i < 4; ++i)
                acc[mf][i] = __builtin_amdgcn_mfma_f32_16x16x32_bf16(afr[mf], bfr[i],
                                                                     acc[mf][i], 0, 0, 0);
    }

    __syncthreads();
    // epilogue: relu -> bf16 tile in LDS (ushort stride 264 == dword 132) -> uint4 store
    ushort* st = (ushort*)lds;
#pragma unroll
    for (int mf = 0; mf < 4; ++mf)
#pragma unroll
        for (int i = 0; i < 4; ++i) {
            int col = wid * 64 + i * 16 + l16;
#pragma unroll
            for (int reg = 0; reg < 4; ++reg) {
                int row = mf * 16 + quad * 4 + reg;
                st[row * 264 + col] = f2bf(fmaxf(acc[mf][i][reg], 0.0f));
            }
        }
    __syncthreads();
#pragma unroll
    for (int it = 0; it < 8; ++it) {
        int i = t + it * 256;
        int r = i >> 5, u4 = i & 31;
        uint4 v = *(uint4*)&lds[r * 132 + u4 * 4];
        *(uint4*)(h1u + (size_t)(r0 + r) * 128 + u4 * 4) = v;
    }
}

// ---------- layer2 head: out = h1_dst @ Ws2 + aggm1 @ Wn2 + b2 ----------
__global__ __launch_bounds__(256) void layer2_k(const ushort* __restrict__ h1,
                                                const uint* __restrict__ aggm,
                                                const float* __restrict__ Ws2,
                                                const float* __restrict__ Wn2,
                                                const float* __restrict__ b2,
                                                float* __restrict__ out, int nrows) {
    int gtid = blockIdx.x * blockDim.x + threadIdx.x;
    int lane = threadIdx.x & 63;
    int row  = gtid >> 6;
    if (row >= nrows) return;

    uint2 hp = *(const uint2*)(h1 + (size_t)row * HF + 4 * lane);
    uint2 ap = *(const uint2*)(aggm + (size_t)row * 128 + 2 * lane);
    float hv[4] = { bflo(hp.x), bfhi(hp.x), bflo(hp.y), bfhi(hp.y) };
    float av[4] = { bflo(ap.x), bfhi(ap.x), bflo(ap.y), bfhi(ap.y) };

    float acc[8];
#pragma unroll
    for (int c = 0; c < 8; ++c) acc[c] = 0.0f;
#pragma unroll
    for (int q = 0; q < 4; ++q) {
        int k = 4 * lane + q;
        const float4* ws = (const float4*)(Ws2 + k * 8);
        const float4* wn = (const float4*)(Wn2 + k * 8);
        float4 s0 = ws[0], s1 = ws[1], n0 = wn[0], n1 = wn[1];
        acc[0] += hv[q] * s0.x + av[q] * n0.x;
        acc[1] += hv[q] * s0.y + av[q] * n0.y;
        acc[2] += hv[q] * s0.z + av[q] * n0.z;
        acc[3] += hv[q] * s0.w + av[q] * n0.w;
        acc[4] += hv[q] * s1.x + av[q] * n1.x;
        acc[5] += hv[q] * s1.y + av[q] * n1.y;
        acc[6] += hv[q] * s1.z + av[q] * n1.z;
        acc[7] += hv[q] * s1.w + av[q] * n1.w;
    }
#pragma unroll
    for (int off = 32; off > 0; off >>= 1)
#pragma unroll
        for (int c = 0; c < 8; ++c) acc[c] += __shfl_down(acc[c], off, 64);

    if (lane == 0) {
        float4 o0 = { acc[0] + b2[0], acc[1] + b2[1], acc[2] + b2[2], acc[3] + b2[3] };
        float4 o1 = { acc[4] + b2[4], acc[5] + b2[5], acc[6] + b2[6], acc[7] + b2[7] };
        *(float4*)(out + (size_t)row * 8)     = o0;
        *(float4*)(out + (size_t)row * 8 + 4) = o1;
    }
}

extern "C" void kernel_launch(void* const* d_in, const int* in_sizes, int n_in,
                              void* d_out, int out_size, void* d_ws, size_t ws_size,
                              hipStream_t stream) {
    const float* x    = (const float*)d_in[0];
    const int*   src0 = (const int*)d_in[1];
    const int*   dst0 = (const int*)d_in[2];
    const int*   src1 = (const int*)d_in[3];
    const int*   dst1 = (const int*)d_in[4];
    const float* emb  = (const float*)d_in[7];
    const float* Ws1  = (const float*)d_in[8];
    const float* Wn1  = (const float*)d_in[9];
    const float* b1   = (const float*)d_in[10];
    const float* Ws2  = (const float*)d_in[11];
    const float* Wn2  = (const float*)d_in[12];
    const float* b2   = (const float*)d_in[13];
    int E0 = in_sizes[1];
    int E1 = in_sizes[3];
    int nsrc = in_sizes[0] / 129;   // 400000

    // ---- workspace layout (~272 MB) ----
    char* p = (char*)d_ws;
    ushort* h         = (ushort*)p;  p += (size_t)nsrc * INF * 2;   // 102.4 MB
    ushort* h1        = (ushort*)p;  p += (size_t)ND0 * HF * 2;     // 102.4 MB
    uint*   aggm      = (uint*)p;    p += (size_t)ND0 * 64 * 4;     // 51.2 MB (reused L1)
    int*    csr       = (int*)p;     p += (size_t)E0 * 4;           // 12.8 MB (reused L1)
    int*    cnt       = (int*)p;     p += (size_t)ND0 * 4;
    int*    row_start = (int*)p;     p += (size_t)ND0 * 4;
    int*    cursor    = (int*)p;     p += (size_t)ND0 * 4;
    int*    bsum      = (int*)p;     p += 256 * 4;
    uint*   Wb        = (uint*)p;    p += 8192 * 16;                // 128 KB frag-major W

    int total0 = nsrc * INF;

    // ---- layer 0/1 ----
    hipMemsetAsync(cnt, 0, (size_t)ND0 * 4, stream);
    gate_k<<<(total0 + 255) / 256, 256, 0, stream>>>(x, emb, h, total0);
    wconv_k<<<32, 256, 0, stream>>>(Ws1, Wn1, Wb);
    hist_k<<<(E0 + 255) / 256, 256, 0, stream>>>(dst0, cnt, E0);
    int nb0 = (ND0 + SCAN_B - 1) / SCAN_B;   // 196
    scan1_k<<<nb0, 256, 0, stream>>>(cnt, row_start, bsum, ND0);
    scan2_k<<<1, 256, 0, stream>>>(bsum, nb0);
    scan3_k<<<(ND0 + 255) / 256, 256, 0, stream>>>(row_start, cursor, bsum, ND0);
    place_k<<<(E0 + 255) / 256, 256, 0, stream>>>(src0, dst0, cursor, csr, E0);
    gather_k<64><<<(ND0 + 3) / 4, 256, 0, stream>>>(csr, row_start, cnt, h, aggm, ND0);
    layer1_mfma_k<<<ND0 / 64, 256, 0, stream>>>((const uint*)h, aggm, Wb, b1,
                                                (uint*)h1, ND0);

    // ---- layer 2 ----
    hipMemsetAsync(cnt, 0, (size_t)ND1 * 4, stream);
    hist_k<<<(E1 + 255) / 256, 256, 0, stream>>>(dst1, cnt, E1);
    int nb1 = (ND1 + SCAN_B - 1) / SCAN_B;   // 98
    scan1_k<<<nb1, 256, 0, stream>>>(cnt, row_start, bsum, ND1);
    scan2_k<<<1, 256, 0, stream>>>(bsum, nb1);
    scan3_k<<<(ND1 + 255) / 256, 256, 0, stream>>>(row_start, cursor, bsum, ND1);
    place_k<<<(E1 + 255) / 256, 256, 0, stream>>>(src1, dst1, cursor, csr, E1);
    gather_k<128><<<(ND1 + 3) / 4, 256, 0, stream>>>(csr, row_start, cnt, h1, aggm, ND1);
    layer2_k<<<(ND1 + 3) / 4, 256, 0, stream>>>(h1, aggm, Ws2, Wn2, b2,
                                                (float*)d_out, ND1);
}

// Round 5
// 1329.936 us; speedup vs baseline: 5.0478x; 1.1768x over previous
//
#include <hip/hip_runtime.h>

typedef unsigned int uint;
typedef unsigned short ushort;
typedef __attribute__((ext_vector_type(8))) short short8;   // 8 bf16 (4 VGPRs)
typedef __attribute__((ext_vector_type(4))) float f32x4;    // MFMA accumulator

// ---------- bf16 helpers (internal storage only; I/O is fp32) ----------
__device__ __forceinline__ float bflo(uint u) { return __uint_as_float(u << 16); }
__device__ __forceinline__ float bfhi(uint u) { return __uint_as_float(u & 0xffff0000u); }
__device__ __forceinline__ ushort f2bf(float f) {
    uint u = __float_as_uint(f);
    u += 0x7fffu + ((u >> 16) & 1u);   // round-to-nearest-even
    return (ushort)(u >> 16);
}
__device__ __forceinline__ uint pack2(float a, float b) {
    return (uint)f2bf(a) | ((uint)f2bf(b) << 16);
}

#define ND0 200000
#define ND1 100000
#define INF 128
#define HF  256
#define BCAP 24576   // max edges per dst-bucket (mean ~16.3k, sigma ~128 -> 64-sigma safe)

// ---------- 1) gate: h[n,f] = feat * sigmoid(emb[cell_id]) ; h bf16 ----------
__global__ __launch_bounds__(256) void gate_k(const float* __restrict__ x,
                                              const float* __restrict__ emb,
                                              ushort* __restrict__ h, int total) {
    int idx = blockIdx.x * blockDim.x + threadIdx.x;
    if (idx >= total) return;
    int node = idx >> 7;
    int f    = idx & 127;
    int cell = (int)x[(size_t)node * 129];
    float e  = emb[cell * INF + f];
    float v  = x[(size_t)node * 129 + 1 + f];
    float g  = 1.0f / (1.0f + __expf(-e));
    h[idx] = f2bf(v * g);
}

// ---------- CSR build: histogram -> scan (row_start) ----------
__global__ __launch_bounds__(256) void hist_k(const int* __restrict__ dst,
                                              int* __restrict__ cnt, int E) {
    int i = blockIdx.x * blockDim.x + threadIdx.x;
    if (i < E) atomicAdd(&cnt[dst[i]], 1);
}

#define SCAN_B 1024
__global__ __launch_bounds__(256) void scan1_k(const int* __restrict__ in,
                                               int* __restrict__ out,
                                               int* __restrict__ bsum, int n) {
    __shared__ int tmp[256];
    int t = threadIdx.x;
    int base = blockIdx.x * SCAN_B;
    int v[4], s = 0;
#pragma unroll
    for (int q = 0; q < 4; ++q) {
        int idx = base + t * 4 + q;
        v[q] = (idx < n) ? in[idx] : 0;
        s += v[q];
    }
    tmp[t] = s; __syncthreads();
    for (int off = 1; off < 256; off <<= 1) {
        int xv = (t >= off) ? tmp[t - off] : 0; __syncthreads();
        tmp[t] += xv; __syncthreads();
    }
    int excl = tmp[t] - s;
#pragma unroll
    for (int q = 0; q < 4; ++q) {
        int idx = base + t * 4 + q;
        if (idx < n) out[idx] = excl;
        excl += v[q];
    }
    if (t == 255) bsum[blockIdx.x] = tmp[255];
}

__global__ __launch_bounds__(256) void scan2_k(int* __restrict__ bsum, int nb) {
    __shared__ int tmp[256];
    int t = threadIdx.x;
    int s = (t < nb) ? bsum[t] : 0;
    tmp[t] = s; __syncthreads();
    for (int off = 1; off < 256; off <<= 1) {
        int xv = (t >= off) ? tmp[t - off] : 0; __syncthreads();
        tmp[t] += xv; __syncthreads();
    }
    if (t < nb) bsum[t] = tmp[t] - s;   // exclusive
}

__global__ __launch_bounds__(256) void scan3_k(int* __restrict__ row_start,
                                               const int* __restrict__ bsum, int n) {
    int i = blockIdx.x * blockDim.x + threadIdx.x;
    if (i < n) row_start[i] += bsum[i >> 10];
}

// ---------- binA: partition edges into 1024-wide dst buckets, packed 4B recs ----------
// rec = (src << 10) | (dst & 1023); bucket region b starts at pairs + b*BCAP.
__global__ __launch_bounds__(256) void binA_k(const int* __restrict__ src,
                                              const int* __restrict__ dst,
                                              uint* __restrict__ pairs,
                                              int* __restrict__ gcur, int E) {
    __shared__ int hist[256];
    __shared__ int curs[256];
    const int CHUNK = 4096;
    int t = threadIdx.x;
    for (int c0 = blockIdx.x * CHUNK; c0 < E; c0 += gridDim.x * CHUNK) {
        int n = min(CHUNK, E - c0);
        hist[t] = 0;
        __syncthreads();
        for (int i = t; i < n; i += 256) atomicAdd(&hist[dst[c0 + i] >> 10], 1);
        __syncthreads();
        curs[t] = hist[t] ? atomicAdd(&gcur[t], hist[t]) : 0;
        __syncthreads();
        for (int i = t; i < n; i += 256) {
            int d = dst[c0 + i];
            int b = d >> 10;
            int p = atomicAdd(&curs[b], 1);
            pairs[(size_t)b * BCAP + p] = ((uint)src[c0 + i] << 10) | (uint)(d & 1023);
        }
        __syncthreads();
    }
}

// ---------- binB: one block per bucket, LDS per-dst cursors, L2-local csr writes ----
__global__ __launch_bounds__(256) void binB_k(const uint* __restrict__ pairs,
                                              const int* __restrict__ gcur,
                                              const int* __restrict__ row_start,
                                              int* __restrict__ csr, int nd) {
    __shared__ int cur[1024];
    int b = blockIdx.x, t = threadIdx.x;
    int dbase = b << 10;
    for (int i = t; i < 1024; i += 256)
        cur[i] = (dbase + i < nd) ? row_start[dbase + i] : 0;
    __syncthreads();
    int ne = gcur[b];
    const uint* bp = pairs + (size_t)b * BCAP;
    for (int i = t; i < ne; i += 256) {
        uint e = bp[i];
        int p = atomicAdd(&cur[e & 1023], 1);
        csr[p] = (int)(e >> 10);
    }
}

// ---------- gather-aggregate: one wave per dst row, mean in registers ----------
template <int FU>
__global__ __launch_bounds__(256) void gather_k(const int* __restrict__ csr,
                                                const int* __restrict__ row_start,
                                                const int* __restrict__ cnt,
                                                const ushort* __restrict__ hsrc,
                                                uint* __restrict__ aggm, int nrows) {
    int w    = (blockIdx.x * blockDim.x + threadIdx.x) >> 6;
    int lane = threadIdx.x & 63;
    if (w >= nrows) return;
    int beg = row_start[w], c = cnt[w], end = beg + c;
    const uint* hb = (const uint*)hsrc;
    float a0 = 0.f, a1 = 0.f, a2 = 0.f, a3 = 0.f;
    int j = beg;
    for (; j + 1 < end; j += 2) {
        int s0 = csr[j], s1 = csr[j + 1];
        if (FU == 64) {
            uint u0 = hb[(size_t)s0 * 64 + lane];
            uint u1 = hb[(size_t)s1 * 64 + lane];
            a0 += bflo(u0) + bflo(u1);
            a1 += bfhi(u0) + bfhi(u1);
        } else {
            uint2 u0 = *(const uint2*)(hb + (size_t)s0 * 128 + 2 * lane);
            uint2 u1 = *(const uint2*)(hb + (size_t)s1 * 128 + 2 * lane);
            a0 += bflo(u0.x) + bflo(u1.x);
            a1 += bfhi(u0.x) + bfhi(u1.x);
            a2 += bflo(u0.y) + bflo(u1.y);
            a3 += bfhi(u0.y) + bfhi(u1.y);
        }
    }
    if (j < end) {
        int s0 = csr[j];
        if (FU == 64) {
            uint u0 = hb[(size_t)s0 * 64 + lane];
            a0 += bflo(u0); a1 += bfhi(u0);
        } else {
            uint2 u0 = *(const uint2*)(hb + (size_t)s0 * 128 + 2 * lane);
            a0 += bflo(u0.x); a1 += bfhi(u0.x);
            a2 += bflo(u0.y); a3 += bfhi(u0.y);
        }
    }
    float inv = 1.0f / fmaxf((float)c, 1.0f);
    if (FU == 64) {
        aggm[(size_t)w * 64 + lane] = pack2(a0 * inv, a1 * inv);
    } else {
        uint2 o;
        o.x = pack2(a0 * inv, a1 * inv);
        o.y = pack2(a2 * inv, a3 * inv);
        *(uint2*)(aggm + (size_t)w * 128 + 2 * lane) = o;
    }
}

// ---------- W pack: [Ws1;Wn1] (256x256 f32) -> B-fragment-major bf16 ----------
__global__ __launch_bounds__(256) void wconv_k(const float* __restrict__ Ws,
                                               const float* __restrict__ Wn,
                                               uint* __restrict__ Wb) {
    int tid  = blockIdx.x * 256 + threadIdx.x;   // 8192 threads
    int lane = tid & 63, nf = (tid >> 6) & 15, ks = tid >> 10;
    int n  = nf * 16 + (lane & 15);
    int k0 = ks * 32 + ((lane >> 4) << 3);
    uint o[4];
#pragma unroll
    for (int p = 0; p < 4; ++p) {
        int k = k0 + 2 * p;
        float a = (k < 128)     ? Ws[(size_t)k * HF + n]       : Wn[(size_t)(k - 128) * HF + n];
        float b = (k + 1 < 128) ? Ws[(size_t)(k + 1) * HF + n] : Wn[(size_t)(k - 127) * HF + n];
        o[p] = pack2(a, b);
    }
    uint4 v = { o[0], o[1], o[2], o[3] };
    *(uint4*)(Wb + (size_t)tid * 4) = v;
}

// ---------- layer1 MFMA: h1 = relu([h|aggm] @ Wb + b1), 64x256 tile/block ----------
__global__ __launch_bounds__(256) void layer1_mfma_k(const uint* __restrict__ hb,
                                                     const uint* __restrict__ aggm,
                                                     const uint* __restrict__ Wb,
                                                     const float* __restrict__ b1,
                                                     uint* __restrict__ h1u, int nrows) {
    __shared__ uint lds[64 * 132];   // 33792 B
    int t = threadIdx.x, lane = t & 63, wid = t >> 6;
    int quad = lane >> 4, l16 = lane & 15;
    int r0 = blockIdx.x * 64;

#pragma unroll
    for (int it = 0; it < 8; ++it) {
        int i = t + it * 256;
        int r = i >> 5, u4 = i & 31;
        const uint* src = (u4 < 16) ? (hb + (size_t)(r0 + r) * 64 + u4 * 4)
                                    : (aggm + (size_t)(r0 + r) * 64 + (u4 - 16) * 4);
        *(uint4*)&lds[r * 132 + u4 * 4] = *(const uint4*)src;
    }

    float bias[4];
#pragma unroll
    for (int i = 0; i < 4; ++i) bias[i] = b1[wid * 64 + i * 16 + l16];
    f32x4 acc[4][4];
#pragma unroll
    for (int mf = 0; mf < 4; ++mf)
#pragma unroll
        for (int i = 0; i < 4; ++i)
            acc[mf][i] = (f32x4){ bias[i], bias[i], bias[i], bias[i] };

    __syncthreads();

#pragma unroll
    for (int ks = 0; ks < 8; ++ks) {
        short8 bfr[4];
#pragma unroll
        for (int i = 0; i < 4; ++i) {
            int nf = wid * 4 + i;
            bfr[i] = *(const short8*)(Wb + (size_t)((ks * 16 + nf) * 64 + lane) * 4);
        }
        short8 afr[4];
#pragma unroll
        for (int mf = 0; mf < 4; ++mf) {
            int r = mf * 16 + l16;
            afr[mf] = *(const short8*)&lds[r * 132 + ks * 16 + quad * 4];
        }
#pragma unroll
        for (int mf = 0; mf < 4; ++mf)
#pragma unroll
            for (int i = 0; i < 4; ++i)
                acc[mf][i] = __builtin_amdgcn_mfma_f32_16x16x32_bf16(afr[mf], bfr[i],
                                                                     acc[mf][i], 0, 0, 0);
    }

    __syncthreads();
    ushort* st = (ushort*)lds;
#pragma unroll
    for (int mf = 0; mf < 4; ++mf)
#pragma unroll
        for (int i = 0; i < 4; ++i) {
            int col = wid * 64 + i * 16 + l16;
#pragma unroll
            for (int reg = 0; reg < 4; ++reg) {
                int row = mf * 16 + quad * 4 + reg;
                st[row * 264 + col] = f2bf(fmaxf(acc[mf][i][reg], 0.0f));
            }
        }
    __syncthreads();
#pragma unroll
    for (int it = 0; it < 8; ++it) {
        int i = t + it * 256;
        int r = i >> 5, u4 = i & 31;
        uint4 v = *(uint4*)&lds[r * 132 + u4 * 4];
        *(uint4*)(h1u + (size_t)(r0 + r) * 128 + u4 * 4) = v;
    }
}

// ---------- layer2 head: out = h1_dst @ Ws2 + aggm1 @ Wn2 + b2 ----------
__global__ __launch_bounds__(256) void layer2_k(const ushort* __restrict__ h1,
                                                const uint* __restrict__ aggm,
                                                const float* __restrict__ Ws2,
                                                const float* __restrict__ Wn2,
                                                const float* __restrict__ b2,
                                                float* __restrict__ out, int nrows) {
    int gtid = blockIdx.x * blockDim.x + threadIdx.x;
    int lane = threadIdx.x & 63;
    int row  = gtid >> 6;
    if (row >= nrows) return;

    uint2 hp = *(const uint2*)(h1 + (size_t)row * HF + 4 * lane);
    uint2 ap = *(const uint2*)(aggm + (size_t)row * 128 + 2 * lane);
    float hv[4] = { bflo(hp.x), bfhi(hp.x), bflo(hp.y), bfhi(hp.y) };
    float av[4] = { bflo(ap.x), bfhi(ap.x), bflo(ap.y), bfhi(ap.y) };

    float acc[8];
#pragma unroll
    for (int c = 0; c < 8; ++c) acc[c] = 0.0f;
#pragma unroll
    for (int q = 0; q < 4; ++q) {
        int k = 4 * lane + q;
        const float4* ws = (const float4*)(Ws2 + k * 8);
        const float4* wn = (const float4*)(Wn2 + k * 8);
        float4 s0 = ws[0], s1 = ws[1], n0 = wn[0], n1 = wn[1];
        acc[0] += hv[q] * s0.x + av[q] * n0.x;
        acc[1] += hv[q] * s0.y + av[q] * n0.y;
        acc[2] += hv[q] * s0.z + av[q] * n0.z;
        acc[3] += hv[q] * s0.w + av[q] * n0.w;
        acc[4] += hv[q] * s1.x + av[q] * n1.x;
        acc[5] += hv[q] * s1.y + av[q] * n1.y;
        acc[6] += hv[q] * s1.z + av[q] * n1.z;
        acc[7] += hv[q] * s1.w + av[q] * n1.w;
    }
#pragma unroll
    for (int off = 32; off > 0; off >>= 1)
#pragma unroll
        for (int c = 0; c < 8; ++c) acc[c] += __shfl_down(acc[c], off, 64);

    if (lane == 0) {
        float4 o0 = { acc[0] + b2[0], acc[1] + b2[1], acc[2] + b2[2], acc[3] + b2[3] };
        float4 o1 = { acc[4] + b2[4], acc[5] + b2[5], acc[6] + b2[6], acc[7] + b2[7] };
        *(float4*)(out + (size_t)row * 8)     = o0;
        *(float4*)(out + (size_t)row * 8 + 4) = o1;
    }
}

extern "C" void kernel_launch(void* const* d_in, const int* in_sizes, int n_in,
                              void* d_out, int out_size, void* d_ws, size_t ws_size,
                              hipStream_t stream) {
    const float* x    = (const float*)d_in[0];
    const int*   src0 = (const int*)d_in[1];
    const int*   dst0 = (const int*)d_in[2];
    const int*   src1 = (const int*)d_in[3];
    const int*   dst1 = (const int*)d_in[4];
    const float* emb  = (const float*)d_in[7];
    const float* Ws1  = (const float*)d_in[8];
    const float* Wn1  = (const float*)d_in[9];
    const float* b1   = (const float*)d_in[10];
    const float* Ws2  = (const float*)d_in[11];
    const float* Wn2  = (const float*)d_in[12];
    const float* b2   = (const float*)d_in[13];
    int E0 = in_sizes[1];
    int E1 = in_sizes[3];
    int nsrc = in_sizes[0] / 129;   // 400000

    // ---- workspace layout (~270 MB) ----
    char* p = (char*)d_ws;
    ushort* h         = (ushort*)p;  p += (size_t)nsrc * INF * 2;   // 102.4 MB
    ushort* h1        = (ushort*)p;  p += (size_t)ND0 * HF * 2;     // 102.4 MB
    uint*   aggm      = (uint*)p;    p += (size_t)ND0 * 64 * 4;     // 51.2 MB
    int*    csr       = (int*)p;     p += (size_t)E0 * 4;           // 12.8 MB
    int*    cnt       = (int*)p;     p += (size_t)ND0 * 4;
    int*    row_start = (int*)p;     p += (size_t)ND0 * 4;
    int*    bsum      = (int*)p;     p += 256 * 4;
    int*    gcur      = (int*)p;     p += 256 * 4;
    uint*   Wb        = (uint*)p;    p += 8192 * 16;                // 128 KB
    // pairs overlaid on aggm (dead during CSR build; stream order makes it safe)
    uint*   pairs     = aggm;        // needs 256*BCAP*4 = 25.2 MB <= 51.2 MB

    int total0 = nsrc * INF;

    // ---- layer 0/1 ----
    hipMemsetAsync(cnt, 0, (size_t)ND0 * 4, stream);
    hipMemsetAsync(gcur, 0, 256 * 4, stream);
    gate_k<<<(total0 + 255) / 256, 256, 0, stream>>>(x, emb, h, total0);
    wconv_k<<<32, 256, 0, stream>>>(Ws1, Wn1, Wb);
    hist_k<<<(E0 + 255) / 256, 256, 0, stream>>>(dst0, cnt, E0);
    int nb0 = (ND0 + SCAN_B - 1) / SCAN_B;   // 196
    scan1_k<<<nb0, 256, 0, stream>>>(cnt, row_start, bsum, ND0);
    scan2_k<<<1, 256, 0, stream>>>(bsum, nb0);
    scan3_k<<<(ND0 + 255) / 256, 256, 0, stream>>>(row_start, bsum, ND0);
    binA_k<<<512, 256, 0, stream>>>(src0, dst0, pairs, gcur, E0);
    binB_k<<<nb0, 256, 0, stream>>>(pairs, gcur, row_start, csr, ND0);
    gather_k<64><<<(ND0 + 3) / 4, 256, 0, stream>>>(csr, row_start, cnt, h, aggm, ND0);
    layer1_mfma_k<<<ND0 / 64, 256, 0, stream>>>((const uint*)h, aggm, Wb, b1,
                                                (uint*)h1, ND0);

    // ---- layer 2 ----
    hipMemsetAsync(cnt, 0, (size_t)ND1 * 4, stream);
    hipMemsetAsync(gcur, 0, 256 * 4, stream);
    hist_k<<<(E1 + 255) / 256, 256, 0, stream>>>(dst1, cnt, E1);
    int nb1 = (ND1 + SCAN_B - 1) / SCAN_B;   // 98
    scan1_k<<<nb1, 256, 0, stream>>>(cnt, row_start, bsum, ND1);
    scan2_k<<<1, 256, 0, stream>>>(bsum, nb1);
    scan3_k<<<(ND1 + 255) / 256, 256, 0, stream>>>(row_start, bsum, ND1);
    binA_k<<<512, 256, 0, stream>>>(src1, dst1, pairs, gcur, E1);
    binB_k<<<nb1, 256, 0, stream>>>(pairs, gcur, row_start, csr, ND1);
    gather_k<128><<<(ND1 + 3) / 4, 256, 0, stream>>>(csr, row_start, cnt, h1, aggm, ND1);
    layer2_k<<<(ND1 + 3) / 4, 256, 0, stream>>>(h1, aggm, Ws2, Wn2, b2,
                                                (float*)d_out, ND1);
}

// Round 6
// 1262.484 us; speedup vs baseline: 5.3175x; 1.0534x over previous
//
#include <hip/hip_runtime.h>

typedef unsigned int uint;
typedef unsigned short ushort;
typedef __attribute__((ext_vector_type(8))) short short8;   // 8 bf16 (4 VGPRs)
typedef __attribute__((ext_vector_type(4))) float f32x4;    // MFMA accumulator

// ---------- bf16 helpers (internal storage only; I/O is fp32) ----------
__device__ __forceinline__ float bflo(uint u) { return __uint_as_float(u << 16); }
__device__ __forceinline__ float bfhi(uint u) { return __uint_as_float(u & 0xffff0000u); }
__device__ __forceinline__ ushort f2bf(float f) {
    uint u = __float_as_uint(f);
    u += 0x7fffu + ((u >> 16) & 1u);   // round-to-nearest-even
    return (ushort)(u >> 16);
}
__device__ __forceinline__ uint pack2(float a, float b) {
    return (uint)f2bf(a) | ((uint)f2bf(b) << 16);
}

#define ND0 200000
#define ND1 100000
#define INF 128
#define HF  256
#define BCAP 24576   // max edges per 1024-dst bucket (mean ~16.3k)

// ---------- 1) gate: h[n,f] = feat * sigmoid(emb[cell_id]) ; h bf16 ----------
__global__ __launch_bounds__(256) void gate_k(const float* __restrict__ x,
                                              const float* __restrict__ emb,
                                              ushort* __restrict__ h, int total) {
    int idx = blockIdx.x * blockDim.x + threadIdx.x;
    if (idx >= total) return;
    int node = idx >> 7;
    int f    = idx & 127;
    int cell = (int)x[(size_t)node * 129];
    float e  = emb[cell * INF + f];
    float v  = x[(size_t)node * 129 + 1 + f];
    float g  = 1.0f / (1.0f + __expf(-e));
    h[idx] = f2bf(v * g);
}

// ---------- CSR build: histogram -> padded scan -> bucket sort -> fill ----------
__global__ __launch_bounds__(256) void hist_k(const int* __restrict__ dst,
                                              int* __restrict__ cnt, int E) {
    int i = blockIdx.x * blockDim.x + threadIdx.x;
    if (i < E) atomicAdd(&cnt[dst[i]], 1);
}

#define SCAN_B 1024
// scans PADDED counts: (cnt+3)&~3 — keeps every CSR row 4-aligned
__global__ __launch_bounds__(256) void scan1_k(const int* __restrict__ in,
                                               int* __restrict__ out,
                                               int* __restrict__ bsum, int n) {
    __shared__ int tmp[256];
    int t = threadIdx.x;
    int base = blockIdx.x * SCAN_B;
    int v[4], s = 0;
#pragma unroll
    for (int q = 0; q < 4; ++q) {
        int idx = base + t * 4 + q;
        v[q] = (idx < n) ? ((in[idx] + 3) & ~3) : 0;
        s += v[q];
    }
    tmp[t] = s; __syncthreads();
    for (int off = 1; off < 256; off <<= 1) {
        int xv = (t >= off) ? tmp[t - off] : 0; __syncthreads();
        tmp[t] += xv; __syncthreads();
    }
    int excl = tmp[t] - s;
#pragma unroll
    for (int q = 0; q < 4; ++q) {
        int idx = base + t * 4 + q;
        if (idx < n) out[idx] = excl;
        excl += v[q];
    }
    if (t == 255) bsum[blockIdx.x] = tmp[255];
}

__global__ __launch_bounds__(256) void scan2_k(int* __restrict__ bsum, int nb) {
    __shared__ int tmp[256];
    int t = threadIdx.x;
    int s = (t < nb) ? bsum[t] : 0;
    tmp[t] = s; __syncthreads();
    for (int off = 1; off < 256; off <<= 1) {
        int xv = (t >= off) ? tmp[t - off] : 0; __syncthreads();
        tmp[t] += xv; __syncthreads();
    }
    if (t < nb) bsum[t] = tmp[t] - s;   // exclusive
}

__global__ __launch_bounds__(256) void scan3_k(int* __restrict__ row_start,
                                               const int* __restrict__ bsum, int n) {
    int i = blockIdx.x * blockDim.x + threadIdx.x;
    if (i < n) row_start[i] += bsum[i >> 10];
}

// binA: partition edges into 1024-wide dst buckets, rec = (src<<10)|(dst&1023)
__global__ __launch_bounds__(256) void binA_k(const int* __restrict__ src,
                                              const int* __restrict__ dst,
                                              uint* __restrict__ pairs,
                                              int* __restrict__ gcur, int E) {
    __shared__ int hist[256];
    __shared__ int curs[256];
    const int CHUNK = 4096;
    int t = threadIdx.x;
    for (int c0 = blockIdx.x * CHUNK; c0 < E; c0 += gridDim.x * CHUNK) {
        int n = min(CHUNK, E - c0);
        hist[t] = 0;
        __syncthreads();
        for (int i = t; i < n; i += 256) atomicAdd(&hist[dst[c0 + i] >> 10], 1);
        __syncthreads();
        curs[t] = hist[t] ? atomicAdd(&gcur[t], hist[t]) : 0;
        __syncthreads();
        for (int i = t; i < n; i += 256) {
            int d = dst[c0 + i];
            int b = d >> 10;
            int p = atomicAdd(&curs[b], 1);
            pairs[(size_t)b * BCAP + p] = ((uint)src[c0 + i] << 10) | (uint)(d & 1023);
        }
        __syncthreads();
    }
}

// binB: one block per bucket, LDS per-dst cursors, L2-local csr writes
__global__ __launch_bounds__(256) void binB_k(const uint* __restrict__ pairs,
                                              const int* __restrict__ gcur,
                                              const int* __restrict__ row_start,
                                              int* __restrict__ csr, int nd) {
    __shared__ int cur[1024];
    int b = blockIdx.x, t = threadIdx.x;
    int dbase = b << 10;
    for (int i = t; i < 1024; i += 256)
        cur[i] = (dbase + i < nd) ? row_start[dbase + i] : 0;
    __syncthreads();
    int ne = gcur[b];
    const uint* bp = pairs + (size_t)b * BCAP;
    for (int i = t; i < ne; i += 256) {
        uint e = bp[i];
        int p = atomicAdd(&cur[e & 1023], 1);
        csr[p] = (int)(e >> 10);
    }
}

// fill pad slots [start+cnt, start+cnt_pad4) with the zero row index
__global__ __launch_bounds__(256) void fill_k(const int* __restrict__ row_start,
                                              const int* __restrict__ cnt,
                                              int* __restrict__ csr, int nd, int zrow) {
    int i = blockIdx.x * blockDim.x + threadIdx.x;
    if (i >= nd) return;
    int s = row_start[i] + cnt[i];
    int e = row_start[i] + ((cnt[i] + 3) & ~3);
    for (int p = s; p < e; ++p) csr[p] = zrow;
}

// ---------- gather4: wave per dst row, 4 independent 256B row loads per iter ----
__global__ __launch_bounds__(256) void gather4_k(const int* __restrict__ csr,
                                                 const int* __restrict__ row_start,
                                                 const int* __restrict__ cnt,
                                                 const ushort* __restrict__ hsrc,
                                                 uint* __restrict__ aggm, int nrows) {
    int w    = (blockIdx.x * blockDim.x + threadIdx.x) >> 6;
    int lane = threadIdx.x & 63;
    if (w >= nrows) return;
    int beg = row_start[w], c = cnt[w];
    int end = beg + ((c + 3) & ~3);
    const uint* hb = (const uint*)hsrc;
    float a0 = 0.f, a1 = 0.f;
    for (int j = beg; j < end; j += 4) {
        int4 s4 = *(const int4*)(csr + j);     // 16B-aligned (rows 4-padded)
        uint u0 = hb[(size_t)s4.x * 64 + lane];
        uint u1 = hb[(size_t)s4.y * 64 + lane];
        uint u2 = hb[(size_t)s4.z * 64 + lane];
        uint u3 = hb[(size_t)s4.w * 64 + lane];
        a0 += (bflo(u0) + bflo(u1)) + (bflo(u2) + bflo(u3));
        a1 += (bfhi(u0) + bfhi(u1)) + (bfhi(u2) + bfhi(u3));
    }
    float inv = 1.0f / fmaxf((float)c, 1.0f);
    aggm[(size_t)w * 64 + lane] = pack2(a0 * inv, a1 * inv);
}

// ---------- W pack: [Ws1;Wn1] (256x256 f32) -> B-fragment-major bf16 ----------
__global__ __launch_bounds__(256) void wconv_k(const float* __restrict__ Ws,
                                               const float* __restrict__ Wn,
                                               uint* __restrict__ Wb) {
    int tid  = blockIdx.x * 256 + threadIdx.x;   // 8192 threads
    int lane = tid & 63, nf = (tid >> 6) & 15, ks = tid >> 10;
    int n  = nf * 16 + (lane & 15);
    int k0 = ks * 32 + ((lane >> 4) << 3);
    uint o[4];
#pragma unroll
    for (int p = 0; p < 4; ++p) {
        int k = k0 + 2 * p;
        float a = (k < 128)     ? Ws[(size_t)k * HF + n]       : Wn[(size_t)(k - 128) * HF + n];
        float b = (k + 1 < 128) ? Ws[(size_t)(k + 1) * HF + n] : Wn[(size_t)(k - 127) * HF + n];
        o[p] = pack2(a, b);
    }
    uint4 v = { o[0], o[1], o[2], o[3] };
    *(uint4*)(Wb + (size_t)tid * 4) = v;
}

// ---------- layer1 MFMA: h1 = relu([h|aggm] @ Wb + b1), 64x256 tile/block ----------
__global__ __launch_bounds__(256) void layer1_mfma_k(const uint* __restrict__ hb,
                                                     const uint* __restrict__ aggm,
                                                     const uint* __restrict__ Wb,
                                                     const float* __restrict__ b1,
                                                     uint* __restrict__ h1u, int nrows) {
    __shared__ uint lds[64 * 132];   // 33792 B
    int t = threadIdx.x, lane = t & 63, wid = t >> 6;
    int quad = lane >> 4, l16 = lane & 15;
    int r0 = blockIdx.x * 64;

#pragma unroll
    for (int it = 0; it < 8; ++it) {
        int i = t + it * 256;
        int r = i >> 5, u4 = i & 31;
        const uint* src = (u4 < 16) ? (hb + (size_t)(r0 + r) * 64 + u4 * 4)
                                    : (aggm + (size_t)(r0 + r) * 64 + (u4 - 16) * 4);
        *(uint4*)&lds[r * 132 + u4 * 4] = *(const uint4*)src;
    }

    float bias[4];
#pragma unroll
    for (int i = 0; i < 4; ++i) bias[i] = b1[wid * 64 + i * 16 + l16];
    f32x4 acc[4][4];
#pragma unroll
    for (int mf = 0; mf < 4; ++mf)
#pragma unroll
        for (int i = 0; i < 4; ++i)
            acc[mf][i] = (f32x4){ bias[i], bias[i], bias[i], bias[i] };

    __syncthreads();

#pragma unroll
    for (int ks = 0; ks < 8; ++ks) {
        short8 bfr[4];
#pragma unroll
        for (int i = 0; i < 4; ++i) {
            int nf = wid * 4 + i;
            bfr[i] = *(const short8*)(Wb + (size_t)((ks * 16 + nf) * 64 + lane) * 4);
        }
        short8 afr[4];
#pragma unroll
        for (int mf = 0; mf < 4; ++mf) {
            int r = mf * 16 + l16;
            afr[mf] = *(const short8*)&lds[r * 132 + ks * 16 + quad * 4];
        }
#pragma unroll
        for (int mf = 0; mf < 4; ++mf)
#pragma unroll
            for (int i = 0; i < 4; ++i)
                acc[mf][i] = __builtin_amdgcn_mfma_f32_16x16x32_bf16(afr[mf], bfr[i],
                                                                     acc[mf][i], 0, 0, 0);
    }

    __syncthreads();
    ushort* st = (ushort*)lds;
#pragma unroll
    for (int mf = 0; mf < 4; ++mf)
#pragma unroll
        for (int i = 0; i < 4; ++i) {
            int col = wid * 64 + i * 16 + l16;
#pragma unroll
            for (int reg = 0; reg < 4; ++reg) {
                int row = mf * 16 + quad * 4 + reg;
                st[row * 264 + col] = f2bf(fmaxf(acc[mf][i][reg], 0.0f));
            }
        }
    __syncthreads();
#pragma unroll
    for (int it = 0; it < 8; ++it) {
        int i = t + it * 256;
        int r = i >> 5, u4 = i & 31;
        uint4 v = *(uint4*)&lds[r * 132 + u4 * 4];
        *(uint4*)(h1u + (size_t)(r0 + r) * 128 + u4 * 4) = v;
    }
}

// ---------- zs: z = h1 @ Wn2 (all rows, fp32); self = h1 @ Ws2 -> out (rows<nd1) ---
__global__ __launch_bounds__(256) void zs_k(const ushort* __restrict__ h1,
                                            const float* __restrict__ Ws2,
                                            const float* __restrict__ Wn2,
                                            float* __restrict__ z,
                                            float* __restrict__ out,
                                            int nd0, int nd1) {
    int gtid = blockIdx.x * blockDim.x + threadIdx.x;
    int lane = threadIdx.x & 63;
    int row  = gtid >> 6;
    if (row >= nd0) return;
    bool self = row < nd1;   // wave-uniform

    uint2 hp = *(const uint2*)(h1 + (size_t)row * HF + 4 * lane);
    float hv[4] = { bflo(hp.x), bfhi(hp.x), bflo(hp.y), bfhi(hp.y) };

    float an[8], as[8];
#pragma unroll
    for (int c = 0; c < 8; ++c) { an[c] = 0.f; as[c] = 0.f; }
#pragma unroll
    for (int q = 0; q < 4; ++q) {
        int k = 4 * lane + q;
        const float4* wn = (const float4*)(Wn2 + k * 8);
        float4 n0 = wn[0], n1 = wn[1];
        an[0] += hv[q] * n0.x; an[1] += hv[q] * n0.y;
        an[2] += hv[q] * n0.z; an[3] += hv[q] * n0.w;
        an[4] += hv[q] * n1.x; an[5] += hv[q] * n1.y;
        an[6] += hv[q] * n1.z; an[7] += hv[q] * n1.w;
        if (self) {
            const float4* ws = (const float4*)(Ws2 + k * 8);
            float4 s0 = ws[0], s1 = ws[1];
            as[0] += hv[q] * s0.x; as[1] += hv[q] * s0.y;
            as[2] += hv[q] * s0.z; as[3] += hv[q] * s0.w;
            as[4] += hv[q] * s1.x; as[5] += hv[q] * s1.y;
            as[6] += hv[q] * s1.z; as[7] += hv[q] * s1.w;
        }
    }
#pragma unroll
    for (int off = 32; off > 0; off >>= 1) {
#pragma unroll
        for (int c = 0; c < 8; ++c) {
            an[c] += __shfl_down(an[c], off, 64);
            as[c] += __shfl_down(as[c], off, 64);
        }
    }
    if (lane == 0) {
        float4 z0 = { an[0], an[1], an[2], an[3] };
        float4 z1 = { an[4], an[5], an[6], an[7] };
        *(float4*)(z + (size_t)row * 8)     = z0;
        *(float4*)(z + (size_t)row * 8 + 4) = z1;
        if (self) {
            float4 s0 = { as[0], as[1], as[2], as[3] };
            float4 s1 = { as[4], as[5], as[6], as[7] };
            *(float4*)(out + (size_t)row * 8)     = s0;
            *(float4*)(out + (size_t)row * 8 + 4) = s1;
        }
    }
}

// ---------- gz: out += mean-gather(z) + b2 ; 8 threads per dst row, unroll 4 ----
__global__ __launch_bounds__(256) void gz_k(const int* __restrict__ csr,
                                            const int* __restrict__ row_start,
                                            const int* __restrict__ cnt,
                                            const float* __restrict__ z,
                                            const float* __restrict__ b2,
                                            float* __restrict__ out, int nrows) {
    int tid = blockIdx.x * 256 + threadIdx.x;
    int d = tid >> 3, c = tid & 7;
    if (d >= nrows) return;
    int beg = row_start[d], n = cnt[d];
    int end = beg + ((n + 3) & ~3);
    float a = 0.f;
    for (int j = beg; j < end; j += 4) {
        int4 s4 = *(const int4*)(csr + j);     // pad slots -> zero z row
        a += z[(size_t)s4.x * 8 + c] + z[(size_t)s4.y * 8 + c]
           + z[(size_t)s4.z * 8 + c] + z[(size_t)s4.w * 8 + c];
    }
    float inv = 1.0f / fmaxf((float)n, 1.0f);
    out[(size_t)d * 8 + c] += a * inv + b2[c];
}

extern "C" void kernel_launch(void* const* d_in, const int* in_sizes, int n_in,
                              void* d_out, int out_size, void* d_ws, size_t ws_size,
                              hipStream_t stream) {
    const float* x    = (const float*)d_in[0];
    const int*   src0 = (const int*)d_in[1];
    const int*   dst0 = (const int*)d_in[2];
    const int*   src1 = (const int*)d_in[3];
    const int*   dst1 = (const int*)d_in[4];
    const float* emb  = (const float*)d_in[7];
    const float* Ws1  = (const float*)d_in[8];
    const float* Wn1  = (const float*)d_in[9];
    const float* b1   = (const float*)d_in[10];
    const float* Ws2  = (const float*)d_in[11];
    const float* Wn2  = (const float*)d_in[12];
    const float* b2   = (const float*)d_in[13];
    int E0 = in_sizes[1];
    int E1 = in_sizes[3];
    int nsrc = in_sizes[0] / 129;   // 400000

    // ---- workspace layout ----
    char* p = (char*)d_ws;
    ushort* h         = (ushort*)p;  p += ((size_t)nsrc + 1) * INF * 2;  // +1 zero row
    ushort* h1        = (ushort*)p;  p += (size_t)ND0 * HF * 2;
    uint*   aggm      = (uint*)p;    p += (size_t)ND0 * 64 * 4;          // 51.2 MB
    int*    csr       = (int*)p;     p += ((size_t)E0 + 3 * (size_t)ND0 + 16) * 4;
    int*    cnt       = (int*)p;     p += (size_t)ND0 * 4;
    int*    row_start = (int*)p;     p += (size_t)ND0 * 4;
    int*    bsum      = (int*)p;     p += 256 * 4;
    int*    gcur      = (int*)p;     p += 256 * 4;
    uint*   Wb        = (uint*)p;    p += 8192 * 16;
    float*  z         = (float*)p;   p += ((size_t)ND0 + 1) * 8 * 4;     // +1 zero row
    // pairs overlaid on aggm (dead during CSR build; stream order makes it safe)
    uint*   pairs     = aggm;        // 256*BCAP*4 = 25.2 MB <= 51.2 MB

    int total0 = nsrc * INF;
    int ZR0 = nsrc;   // zero row index in h
    int ZR1 = ND0;    // zero row index in z

    // ---- layer 0/1 ----
    hipMemsetAsync(cnt, 0, (size_t)ND0 * 4, stream);
    hipMemsetAsync(gcur, 0, 256 * 4, stream);
    hipMemsetAsync(h + (size_t)ZR0 * INF, 0, INF * 2, stream);
    gate_k<<<(total0 + 255) / 256, 256, 0, stream>>>(x, emb, h, total0);
    wconv_k<<<32, 256, 0, stream>>>(Ws1, Wn1, Wb);
    hist_k<<<(E0 + 255) / 256, 256, 0, stream>>>(dst0, cnt, E0);
    int nb0 = (ND0 + SCAN_B - 1) / SCAN_B;   // 196
    scan1_k<<<nb0, 256, 0, stream>>>(cnt, row_start, bsum, ND0);
    scan2_k<<<1, 256, 0, stream>>>(bsum, nb0);
    scan3_k<<<(ND0 + 255) / 256, 256, 0, stream>>>(row_start, bsum, ND0);
    binA_k<<<512, 256, 0, stream>>>(src0, dst0, pairs, gcur, E0);
    binB_k<<<nb0, 256, 0, stream>>>(pairs, gcur, row_start, csr, ND0);
    fill_k<<<(ND0 + 255) / 256, 256, 0, stream>>>(row_start, cnt, csr, ND0, ZR0);
    gather4_k<<<(ND0 + 3) / 4, 256, 0, stream>>>(csr, row_start, cnt, h, aggm, ND0);
    layer1_mfma_k<<<ND0 / 64, 256, 0, stream>>>((const uint*)h, aggm, Wb, b1,
                                                (uint*)h1, ND0);

    // ---- layer 2 (z = h1@Wn2 first; gather 32B z rows instead of 512B h1 rows) ----
    hipMemsetAsync(cnt, 0, (size_t)ND1 * 4, stream);
    hipMemsetAsync(gcur, 0, 256 * 4, stream);
    hipMemsetAsync(z + (size_t)ZR1 * 8, 0, 8 * 4, stream);
    hist_k<<<(E1 + 255) / 256, 256, 0, stream>>>(dst1, cnt, E1);
    int nb1 = (ND1 + SCAN_B - 1) / SCAN_B;   // 98
    scan1_k<<<nb1, 256, 0, stream>>>(cnt, row_start, bsum, ND1);
    scan2_k<<<1, 256, 0, stream>>>(bsum, nb1);
    scan3_k<<<(ND1 + 255) / 256, 256, 0, stream>>>(row_start, bsum, ND1);
    binA_k<<<512, 256, 0, stream>>>(src1, dst1, pairs, gcur, E1);
    binB_k<<<nb1, 256, 0, stream>>>(pairs, gcur, row_start, csr, ND1);
    fill_k<<<(ND1 + 255) / 256, 256, 0, stream>>>(row_start, cnt, csr, ND1, ZR1);
    zs_k<<<(ND0 + 3) / 4, 256, 0, stream>>>(h1, Ws2, Wn2, z, (float*)d_out, ND0, ND1);
    gz_k<<<(ND1 * 8 + 255) / 256, 256, 0, stream>>>(csr, row_start, cnt, z, b2,
                                                    (float*)d_out, ND1);
}

// Round 7
// 1013.588 us; speedup vs baseline: 6.6233x; 1.2456x over previous
//
#include <hip/hip_runtime.h>

typedef unsigned int uint;
typedef unsigned short ushort;
typedef __attribute__((ext_vector_type(8))) short short8;   // 8 bf16 (4 VGPRs)
typedef __attribute__((ext_vector_type(4))) float f32x4;    // MFMA accumulator

// ---------- bf16 helpers (internal storage only; I/O is fp32) ----------
__device__ __forceinline__ float bflo(uint u) { return __uint_as_float(u << 16); }
__device__ __forceinline__ float bfhi(uint u) { return __uint_as_float(u & 0xffff0000u); }
__device__ __forceinline__ ushort f2bf(float f) {
    uint u = __float_as_uint(f);
    u += 0x7fffu + ((u >> 16) & 1u);   // round-to-nearest-even
    return (ushort)(u >> 16);
}
__device__ __forceinline__ uint pack2(float a, float b) {
    return (uint)f2bf(a) | ((uint)f2bf(b) << 16);
}

#define ND0 200000
#define ND1 100000
#define INF 128
#define HF  256
#define BCAP 24576   // max edges per 1024-dst bucket (mean ~16.3k)

// ---------- 1) gate: h[n,f] = feat * sigmoid(emb[cell_id]) ; h bf16 ----------
__global__ __launch_bounds__(256) void gate_k(const float* __restrict__ x,
                                              const float* __restrict__ emb,
                                              ushort* __restrict__ h, int total) {
    int idx = blockIdx.x * blockDim.x + threadIdx.x;
    if (idx >= total) return;
    int node = idx >> 7;
    int f    = idx & 127;
    int cell = (int)x[(size_t)node * 129];
    float e  = emb[cell * INF + f];
    float v  = x[(size_t)node * 129 + 1 + f];
    float g  = 1.0f / (1.0f + __expf(-e));
    h[idx] = f2bf(v * g);
}

// ---------- CSR build: histogram -> padded scan -> bucket sort -> fill ----------
__global__ __launch_bounds__(256) void hist_k(const int* __restrict__ dst,
                                              int* __restrict__ cnt, int E) {
    int i = blockIdx.x * blockDim.x + threadIdx.x;
    if (i < E) atomicAdd(&cnt[dst[i]], 1);
}

#define SCAN_B 1024
// scans PADDED counts: (cnt+3)&~3 — keeps every CSR row 4-aligned
__global__ __launch_bounds__(256) void scan1_k(const int* __restrict__ in,
                                               int* __restrict__ out,
                                               int* __restrict__ bsum, int n) {
    __shared__ int tmp[256];
    int t = threadIdx.x;
    int base = blockIdx.x * SCAN_B;
    int v[4], s = 0;
#pragma unroll
    for (int q = 0; q < 4; ++q) {
        int idx = base + t * 4 + q;
        v[q] = (idx < n) ? ((in[idx] + 3) & ~3) : 0;
        s += v[q];
    }
    tmp[t] = s; __syncthreads();
    for (int off = 1; off < 256; off <<= 1) {
        int xv = (t >= off) ? tmp[t - off] : 0; __syncthreads();
        tmp[t] += xv; __syncthreads();
    }
    int excl = tmp[t] - s;
#pragma unroll
    for (int q = 0; q < 4; ++q) {
        int idx = base + t * 4 + q;
        if (idx < n) out[idx] = excl;
        excl += v[q];
    }
    if (t == 255) bsum[blockIdx.x] = tmp[255];
}

__global__ __launch_bounds__(256) void scan2_k(int* __restrict__ bsum, int nb) {
    __shared__ int tmp[256];
    int t = threadIdx.x;
    int s = (t < nb) ? bsum[t] : 0;
    tmp[t] = s; __syncthreads();
    for (int off = 1; off < 256; off <<= 1) {
        int xv = (t >= off) ? tmp[t - off] : 0; __syncthreads();
        tmp[t] += xv; __syncthreads();
    }
    if (t < nb) bsum[t] = tmp[t] - s;   // exclusive
}

__global__ __launch_bounds__(256) void scan3_k(int* __restrict__ row_start,
                                               const int* __restrict__ bsum, int n) {
    int i = blockIdx.x * blockDim.x + threadIdx.x;
    if (i < n) row_start[i] += bsum[i >> 10];
}

// binA: partition edges into 1024-wide dst buckets, rec = (src<<10)|(dst&1023)
__global__ __launch_bounds__(256) void binA_k(const int* __restrict__ src,
                                              const int* __restrict__ dst,
                                              uint* __restrict__ pairs,
                                              int* __restrict__ gcur, int E) {
    __shared__ int hist[256];
    __shared__ int curs[256];
    const int CHUNK = 4096;
    int t = threadIdx.x;
    for (int c0 = blockIdx.x * CHUNK; c0 < E; c0 += gridDim.x * CHUNK) {
        int n = min(CHUNK, E - c0);
        hist[t] = 0;
        __syncthreads();
        for (int i = t; i < n; i += 256) atomicAdd(&hist[dst[c0 + i] >> 10], 1);
        __syncthreads();
        curs[t] = hist[t] ? atomicAdd(&gcur[t], hist[t]) : 0;
        __syncthreads();
        for (int i = t; i < n; i += 256) {
            int d = dst[c0 + i];
            int b = d >> 10;
            int p = atomicAdd(&curs[b], 1);
            pairs[(size_t)b * BCAP + p] = ((uint)src[c0 + i] << 10) | (uint)(d & 1023);
        }
        __syncthreads();
    }
}

// binB: one block per bucket, LDS per-dst cursors, L2-local csr writes
__global__ __launch_bounds__(256) void binB_k(const uint* __restrict__ pairs,
                                              const int* __restrict__ gcur,
                                              const int* __restrict__ row_start,
                                              int* __restrict__ csr, int nd) {
    __shared__ int cur[1024];
    int b = blockIdx.x, t = threadIdx.x;
    int dbase = b << 10;
    for (int i = t; i < 1024; i += 256)
        cur[i] = (dbase + i < nd) ? row_start[dbase + i] : 0;
    __syncthreads();
    int ne = gcur[b];
    const uint* bp = pairs + (size_t)b * BCAP;
    for (int i = t; i < ne; i += 256) {
        uint e = bp[i];
        int p = atomicAdd(&cur[e & 1023], 1);
        csr[p] = (int)(e >> 10);
    }
}

// fill pad slots [start+cnt, start+cnt_pad4) with the zero row index
__global__ __launch_bounds__(256) void fill_k(const int* __restrict__ row_start,
                                              const int* __restrict__ cnt,
                                              int* __restrict__ csr, int nd, int zrow) {
    int i = blockIdx.x * blockDim.x + threadIdx.x;
    if (i >= nd) return;
    int s = row_start[i] + cnt[i];
    int e = row_start[i] + ((cnt[i] + 3) & ~3);
    for (int p = s; p < e; ++p) csr[p] = zrow;
}

// ---------- gather4: wave per dst row, 4 independent 256B row loads per iter ----
__global__ __launch_bounds__(256) void gather4_k(const int* __restrict__ csr,
                                                 const int* __restrict__ row_start,
                                                 const int* __restrict__ cnt,
                                                 const ushort* __restrict__ hsrc,
                                                 uint* __restrict__ aggm, int nrows) {
    int w    = (blockIdx.x * blockDim.x + threadIdx.x) >> 6;
    int lane = threadIdx.x & 63;
    if (w >= nrows) return;
    int beg = row_start[w], c = cnt[w];
    int end = beg + ((c + 3) & ~3);
    const uint* hb = (const uint*)hsrc;
    float a0 = 0.f, a1 = 0.f;
    for (int j = beg; j < end; j += 4) {
        int4 s4 = *(const int4*)(csr + j);     // 16B-aligned (rows 4-padded)
        uint u0 = hb[(size_t)s4.x * 64 + lane];
        uint u1 = hb[(size_t)s4.y * 64 + lane];
        uint u2 = hb[(size_t)s4.z * 64 + lane];
        uint u3 = hb[(size_t)s4.w * 64 + lane];
        a0 += (bflo(u0) + bflo(u1)) + (bflo(u2) + bflo(u3));
        a1 += (bfhi(u0) + bfhi(u1)) + (bfhi(u2) + bfhi(u3));
    }
    float inv = 1.0f / fmaxf((float)c, 1.0f);
    aggm[(size_t)w * 64 + lane] = pack2(a0 * inv, a1 * inv);
}

// ---------- W pack: [Ws1;Wn1] (256x256 f32) -> B-fragment-major bf16 ----------
__global__ __launch_bounds__(256) void wconv_k(const float* __restrict__ Ws,
                                               const float* __restrict__ Wn,
                                               uint* __restrict__ Wb) {
    int tid  = blockIdx.x * 256 + threadIdx.x;   // 8192 threads
    int lane = tid & 63, nf = (tid >> 6) & 15, ks = tid >> 10;
    int n  = nf * 16 + (lane & 15);
    int k0 = ks * 32 + ((lane >> 4) << 3);
    uint o[4];
#pragma unroll
    for (int p = 0; p < 4; ++p) {
        int k = k0 + 2 * p;
        float a = (k < 128)     ? Ws[(size_t)k * HF + n]       : Wn[(size_t)(k - 128) * HF + n];
        float b = (k + 1 < 128) ? Ws[(size_t)(k + 1) * HF + n] : Wn[(size_t)(k - 127) * HF + n];
        o[p] = pack2(a, b);
    }
    uint4 v = { o[0], o[1], o[2], o[3] };
    *(uint4*)(Wb + (size_t)tid * 4) = v;
}

// ---------- W pack 2: B2 = [Wn2 (cols 0-7) | Ws2 (cols 8-15)], 256x16 bf16 -----
// frag(ks,lane): B2[k = ks*32 + (lane>>4)*8 + j][n = lane&15], j=0..7 -> uint4
__global__ __launch_bounds__(256) void wpack2_k(const float* __restrict__ Ws2,
                                                const float* __restrict__ Wn2,
                                                uint* __restrict__ Wb2) {
    int tid = blockIdx.x * 256 + threadIdx.x;   // 512 threads
    if (tid >= 512) return;
    int lane = tid & 63, ks = tid >> 6;
    int n  = lane & 15;
    int k0 = ks * 32 + ((lane >> 4) << 3);
    const float* W = (n < 8) ? Wn2 : Ws2;
    int c = n & 7;
    uint o[4];
#pragma unroll
    for (int p = 0; p < 4; ++p) {
        int k = k0 + 2 * p;
        o[p] = pack2(W[(size_t)k * 8 + c], W[(size_t)(k + 1) * 8 + c]);
    }
    uint4 v = { o[0], o[1], o[2], o[3] };
    *(uint4*)(Wb2 + (size_t)tid * 4) = v;
}

// ---------- layer1 MFMA: h1 = relu([h|aggm] @ Wb + b1), 64x256 tile/block ----------
__global__ __launch_bounds__(256) void layer1_mfma_k(const uint* __restrict__ hb,
                                                     const uint* __restrict__ aggm,
                                                     const uint* __restrict__ Wb,
                                                     const float* __restrict__ b1,
                                                     uint* __restrict__ h1u, int nrows) {
    __shared__ uint lds[64 * 132];   // 33792 B
    int t = threadIdx.x, lane = t & 63, wid = t >> 6;
    int quad = lane >> 4, l16 = lane & 15;
    int r0 = blockIdx.x * 64;

#pragma unroll
    for (int it = 0; it < 8; ++it) {
        int i = t + it * 256;
        int r = i >> 5, u4 = i & 31;
        const uint* src = (u4 < 16) ? (hb + (size_t)(r0 + r) * 64 + u4 * 4)
                                    : (aggm + (size_t)(r0 + r) * 64 + (u4 - 16) * 4);
        *(uint4*)&lds[r * 132 + u4 * 4] = *(const uint4*)src;
    }

    float bias[4];
#pragma unroll
    for (int i = 0; i < 4; ++i) bias[i] = b1[wid * 64 + i * 16 + l16];
    f32x4 acc[4][4];
#pragma unroll
    for (int mf = 0; mf < 4; ++mf)
#pragma unroll
        for (int i = 0; i < 4; ++i)
            acc[mf][i] = (f32x4){ bias[i], bias[i], bias[i], bias[i] };

    __syncthreads();

#pragma unroll
    for (int ks = 0; ks < 8; ++ks) {
        short8 bfr[4];
#pragma unroll
        for (int i = 0; i < 4; ++i) {
            int nf = wid * 4 + i;
            bfr[i] = *(const short8*)(Wb + (size_t)((ks * 16 + nf) * 64 + lane) * 4);
        }
        short8 afr[4];
#pragma unroll
        for (int mf = 0; mf < 4; ++mf) {
            int r = mf * 16 + l16;
            afr[mf] = *(const short8*)&lds[r * 132 + ks * 16 + quad * 4];
        }
#pragma unroll
        for (int mf = 0; mf < 4; ++mf)
#pragma unroll
            for (int i = 0; i < 4; ++i)
                acc[mf][i] = __builtin_amdgcn_mfma_f32_16x16x32_bf16(afr[mf], bfr[i],
                                                                     acc[mf][i], 0, 0, 0);
    }

    __syncthreads();
    ushort* st = (ushort*)lds;
#pragma unroll
    for (int mf = 0; mf < 4; ++mf)
#pragma unroll
        for (int i = 0; i < 4; ++i) {
            int col = wid * 64 + i * 16 + l16;
#pragma unroll
            for (int reg = 0; reg < 4; ++reg) {
                int row = mf * 16 + quad * 4 + reg;
                st[row * 264 + col] = f2bf(fmaxf(acc[mf][i][reg], 0.0f));
            }
        }
    __syncthreads();
#pragma unroll
    for (int it = 0; it < 8; ++it) {
        int i = t + it * 256;
        int r = i >> 5, u4 = i & 31;
        uint4 v = *(uint4*)&lds[r * 132 + u4 * 4];
        *(uint4*)(h1u + (size_t)(r0 + r) * 128 + u4 * 4) = v;
    }
}

// ---------- zs MFMA: one wave = 16 rows x 16 cols; cols 0-7 -> z, 8-15 -> out ----
__global__ __launch_bounds__(256) void zs_mfma_k(const uint* __restrict__ h1u,
                                                 const uint* __restrict__ Wb2,
                                                 float* __restrict__ z,
                                                 float* __restrict__ out,
                                                 int nd0, int nd1) {
    int t = threadIdx.x, lane = t & 63, wid = t >> 6;
    int quad = lane >> 4, l16 = lane & 15;
    int w = blockIdx.x * 4 + wid;
    int r0 = w * 16;
    if (r0 >= nd0) return;

    f32x4 acc = (f32x4){ 0.f, 0.f, 0.f, 0.f };
#pragma unroll
    for (int ks = 0; ks < 8; ++ks) {
        short8 a = *(const short8*)(h1u + (size_t)(r0 + l16) * 128 + ks * 16 + quad * 4);
        short8 b = *(const short8*)(Wb2 + (size_t)(ks * 64 + lane) * 4);
        acc = __builtin_amdgcn_mfma_f32_16x16x32_bf16(a, b, acc, 0, 0, 0);
    }
    // C layout: col = l16, row_in_tile = quad*4 + reg
#pragma unroll
    for (int reg = 0; reg < 4; ++reg) {
        int r = r0 + quad * 4 + reg;
        if (l16 < 8) z[(size_t)r * 8 + l16] = acc[reg];
        else if (r < nd1) out[(size_t)r * 8 + (l16 - 8)] = acc[reg];
    }
}

// ---------- gz: out += mean-gather(z) + b2 ; 8 threads per dst row, unroll 4 ----
__global__ __launch_bounds__(256) void gz_k(const int* __restrict__ csr,
                                            const int* __restrict__ row_start,
                                            const int* __restrict__ cnt,
                                            const float* __restrict__ z,
                                            const float* __restrict__ b2,
                                            float* __restrict__ out, int nrows) {
    int tid = blockIdx.x * 256 + threadIdx.x;
    int d = tid >> 3, c = tid & 7;
    if (d >= nrows) return;
    int beg = row_start[d], n = cnt[d];
    int end = beg + ((n + 3) & ~3);
    float a = 0.f;
    for (int j = beg; j < end; j += 4) {
        int4 s4 = *(const int4*)(csr + j);     // pad slots -> zero z row
        a += z[(size_t)s4.x * 8 + c] + z[(size_t)s4.y * 8 + c]
           + z[(size_t)s4.z * 8 + c] + z[(size_t)s4.w * 8 + c];
    }
    float inv = 1.0f / fmaxf((float)n, 1.0f);
    out[(size_t)d * 8 + c] += a * inv + b2[c];
}

extern "C" void kernel_launch(void* const* d_in, const int* in_sizes, int n_in,
                              void* d_out, int out_size, void* d_ws, size_t ws_size,
                              hipStream_t stream) {
    const float* x    = (const float*)d_in[0];
    const int*   src0 = (const int*)d_in[1];
    const int*   dst0 = (const int*)d_in[2];
    const int*   src1 = (const int*)d_in[3];
    const int*   dst1 = (const int*)d_in[4];
    const float* emb  = (const float*)d_in[7];
    const float* Ws1  = (const float*)d_in[8];
    const float* Wn1  = (const float*)d_in[9];
    const float* b1   = (const float*)d_in[10];
    const float* Ws2  = (const float*)d_in[11];
    const float* Wn2  = (const float*)d_in[12];
    const float* b2   = (const float*)d_in[13];
    int E0 = in_sizes[1];
    int E1 = in_sizes[3];
    int nsrc = in_sizes[0] / 129;   // 400000

    // ---- workspace layout ----
    char* p = (char*)d_ws;
    ushort* h         = (ushort*)p;  p += ((size_t)nsrc + 1) * INF * 2;  // +1 zero row
    ushort* h1        = (ushort*)p;  p += (size_t)ND0 * HF * 2;
    uint*   aggm      = (uint*)p;    p += (size_t)ND0 * 64 * 4;          // 51.2 MB
    int*    csr       = (int*)p;     p += ((size_t)E0 + 3 * (size_t)ND0 + 16) * 4;
    int*    cnt       = (int*)p;     p += (size_t)ND0 * 4;
    int*    row_start = (int*)p;     p += (size_t)ND0 * 4;
    int*    bsum      = (int*)p;     p += 256 * 4;
    int*    gcur      = (int*)p;     p += 256 * 4;
    uint*   Wb        = (uint*)p;    p += 8192 * 16;
    uint*   Wb2       = (uint*)p;    p += 512 * 16;                      // 8 KB
    float*  z         = (float*)p;   p += ((size_t)ND0 + 1) * 8 * 4;     // +1 zero row
    // pairs overlaid on aggm (dead during CSR build; stream order makes it safe)
    uint*   pairs     = aggm;        // 256*BCAP*4 = 25.2 MB <= 51.2 MB

    int total0 = nsrc * INF;
    int ZR0 = nsrc;   // zero row index in h
    int ZR1 = ND0;    // zero row index in z

    // ---- layer 0/1 ----
    hipMemsetAsync(cnt, 0, (size_t)ND0 * 4, stream);
    hipMemsetAsync(gcur, 0, 256 * 4, stream);
    hipMemsetAsync(h + (size_t)ZR0 * INF, 0, INF * 2, stream);
    gate_k<<<(total0 + 255) / 256, 256, 0, stream>>>(x, emb, h, total0);
    wconv_k<<<32, 256, 0, stream>>>(Ws1, Wn1, Wb);
    wpack2_k<<<2, 256, 0, stream>>>(Ws2, Wn2, Wb2);
    hist_k<<<(E0 + 255) / 256, 256, 0, stream>>>(dst0, cnt, E0);
    int nb0 = (ND0 + SCAN_B - 1) / SCAN_B;   // 196
    scan1_k<<<nb0, 256, 0, stream>>>(cnt, row_start, bsum, ND0);
    scan2_k<<<1, 256, 0, stream>>>(bsum, nb0);
    scan3_k<<<(ND0 + 255) / 256, 256, 0, stream>>>(row_start, bsum, ND0);
    binA_k<<<512, 256, 0, stream>>>(src0, dst0, pairs, gcur, E0);
    binB_k<<<nb0, 256, 0, stream>>>(pairs, gcur, row_start, csr, ND0);
    fill_k<<<(ND0 + 255) / 256, 256, 0, stream>>>(row_start, cnt, csr, ND0, ZR0);
    gather4_k<<<(ND0 + 3) / 4, 256, 0, stream>>>(csr, row_start, cnt, h, aggm, ND0);
    layer1_mfma_k<<<ND0 / 64, 256, 0, stream>>>((const uint*)h, aggm, Wb, b1,
                                                (uint*)h1, ND0);

    // ---- layer 2 (z = h1@Wn2, self = h1@Ws2 via one MFMA pass; gather 32B z rows) --
    hipMemsetAsync(cnt, 0, (size_t)ND1 * 4, stream);
    hipMemsetAsync(gcur, 0, 256 * 4, stream);
    hipMemsetAsync(z + (size_t)ZR1 * 8, 0, 8 * 4, stream);
    hist_k<<<(E1 + 255) / 256, 256, 0, stream>>>(dst1, cnt, E1);
    int nb1 = (ND1 + SCAN_B - 1) / SCAN_B;   // 98
    scan1_k<<<nb1, 256, 0, stream>>>(cnt, row_start, bsum, ND1);
    scan2_k<<<1, 256, 0, stream>>>(bsum, nb1);
    scan3_k<<<(ND1 + 255) / 256, 256, 0, stream>>>(row_start, bsum, ND1);
    binA_k<<<512, 256, 0, stream>>>(src1, dst1, pairs, gcur, E1);
    binB_k<<<nb1, 256, 0, stream>>>(pairs, gcur, row_start, csr, ND1);
    fill_k<<<(ND1 + 255) / 256, 256, 0, stream>>>(row_start, cnt, csr, ND1, ZR1);
    zs_mfma_k<<<(ND0 / 16 + 3) / 4, 256, 0, stream>>>((const uint*)h1, Wb2, z,
                                                      (float*)d_out, ND0, ND1);
    gz_k<<<(ND1 * 8 + 255) / 256, 256, 0, stream>>>(csr, row_start, cnt, z, b2,
                                                    (float*)d_out, ND1);
}

// Round 8
// 937.572 us; speedup vs baseline: 7.1602x; 1.0811x over previous
//
#include <hip/hip_runtime.h>

typedef unsigned int uint;
typedef unsigned short ushort;
typedef __attribute__((ext_vector_type(8))) short short8;   // 8 bf16 (4 VGPRs)
typedef __attribute__((ext_vector_type(4))) float f32x4;    // MFMA accumulator

// ---------- bf16 helpers (internal storage only; I/O is fp32) ----------
__device__ __forceinline__ float bflo(uint u) { return __uint_as_float(u << 16); }
__device__ __forceinline__ float bfhi(uint u) { return __uint_as_float(u & 0xffff0000u); }
__device__ __forceinline__ ushort f2bf(float f) {
    uint u = __float_as_uint(f);
    u += 0x7fffu + ((u >> 16) & 1u);   // round-to-nearest-even
    return (ushort)(u >> 16);
}
__device__ __forceinline__ uint pack2(float a, float b) {
    return (uint)f2bf(a) | ((uint)f2bf(b) << 16);
}
__device__ __forceinline__ float sigm(float e) { return 1.0f / (1.0f + __expf(-e)); }

#define ND0 200000
#define ND1 100000
#define INF 128
#define HF  256
#define BCAP 24576   // max edges per 1024-dst bucket (mean ~16.3k)

// ---------- 1) gate: h[n,f] = feat * sigmoid(emb[cell_id]) ; h bf16 ----------
// 16 threads per node, 8 feats each: 2x 16B (unaligned-ok) x loads, 2x float4 emb,
// one packed uint4 store. 8x fewer store instructions than thread-per-feat.
__global__ __launch_bounds__(256) void gate_k(const float* __restrict__ x,
                                              const float* __restrict__ emb,
                                              ushort* __restrict__ h, int nnodes) {
    int tid  = blockIdx.x * 256 + threadIdx.x;
    int node = tid >> 4, tq = tid & 15;
    if (node >= nnodes) return;
    const float* xr = x + (size_t)node * 129;
    int cell = (int)xr[0];
    int f0 = tq * 8;
    const float* er = emb + cell * INF + f0;
    float4 e0 = *(const float4*)er;
    float4 e1 = *(const float4*)(er + 4);
    float v[8];
    __builtin_memcpy(&v[0], xr + 1 + f0, 16);      // 4B-aligned dwordx4
    __builtin_memcpy(&v[4], xr + 5 + f0, 16);
    uint4 o;
    o.x = pack2(v[0] * sigm(e0.x), v[1] * sigm(e0.y));
    o.y = pack2(v[2] * sigm(e0.z), v[3] * sigm(e0.w));
    o.z = pack2(v[4] * sigm(e1.x), v[5] * sigm(e1.y));
    o.w = pack2(v[6] * sigm(e1.z), v[7] * sigm(e1.w));
    *(uint4*)(h + (size_t)node * INF + f0) = o;
}

// ---------- CSR build: histogram -> padded scan -> bucket sort -> fill ----------
__global__ __launch_bounds__(256) void hist_k(const int* __restrict__ dst,
                                              int* __restrict__ cnt, int E) {
    int i = blockIdx.x * blockDim.x + threadIdx.x;
    if (i < E) atomicAdd(&cnt[dst[i]], 1);
}

#define SCAN_B 1024
// scans PADDED counts: (cnt+3)&~3 — keeps every CSR row 4-aligned
__global__ __launch_bounds__(256) void scan1_k(const int* __restrict__ in,
                                               int* __restrict__ out,
                                               int* __restrict__ bsum, int n) {
    __shared__ int tmp[256];
    int t = threadIdx.x;
    int base = blockIdx.x * SCAN_B;
    int v[4], s = 0;
#pragma unroll
    for (int q = 0; q < 4; ++q) {
        int idx = base + t * 4 + q;
        v[q] = (idx < n) ? ((in[idx] + 3) & ~3) : 0;
        s += v[q];
    }
    tmp[t] = s; __syncthreads();
    for (int off = 1; off < 256; off <<= 1) {
        int xv = (t >= off) ? tmp[t - off] : 0; __syncthreads();
        tmp[t] += xv; __syncthreads();
    }
    int excl = tmp[t] - s;
#pragma unroll
    for (int q = 0; q < 4; ++q) {
        int idx = base + t * 4 + q;
        if (idx < n) out[idx] = excl;
        excl += v[q];
    }
    if (t == 255) bsum[blockIdx.x] = tmp[255];
}

__global__ __launch_bounds__(256) void scan2_k(int* __restrict__ bsum, int nb) {
    __shared__ int tmp[256];
    int t = threadIdx.x;
    int s = (t < nb) ? bsum[t] : 0;
    tmp[t] = s; __syncthreads();
    for (int off = 1; off < 256; off <<= 1) {
        int xv = (t >= off) ? tmp[t - off] : 0; __syncthreads();
        tmp[t] += xv; __syncthreads();
    }
    if (t < nb) bsum[t] = tmp[t] - s;   // exclusive
}

__global__ __launch_bounds__(256) void scan3_k(int* __restrict__ row_start,
                                               const int* __restrict__ bsum, int n) {
    int i = blockIdx.x * blockDim.x + threadIdx.x;
    if (i < n) row_start[i] += bsum[i >> 10];
}

// binA: partition edges into 1024-wide dst buckets, rec = (src<<10)|(dst&1023)
__global__ __launch_bounds__(256) void binA_k(const int* __restrict__ src,
                                              const int* __restrict__ dst,
                                              uint* __restrict__ pairs,
                                              int* __restrict__ gcur, int E) {
    __shared__ int hist[256];
    __shared__ int curs[256];
    const int CHUNK = 4096;
    int t = threadIdx.x;
    for (int c0 = blockIdx.x * CHUNK; c0 < E; c0 += gridDim.x * CHUNK) {
        int n = min(CHUNK, E - c0);
        hist[t] = 0;
        __syncthreads();
        for (int i = t; i < n; i += 256) atomicAdd(&hist[dst[c0 + i] >> 10], 1);
        __syncthreads();
        curs[t] = hist[t] ? atomicAdd(&gcur[t], hist[t]) : 0;
        __syncthreads();
        for (int i = t; i < n; i += 256) {
            int d = dst[c0 + i];
            int b = d >> 10;
            int p = atomicAdd(&curs[b], 1);
            pairs[(size_t)b * BCAP + p] = ((uint)src[c0 + i] << 10) | (uint)(d & 1023);
        }
        __syncthreads();
    }
}

// binB: one block per bucket, LDS per-dst cursors, L2-local csr writes
__global__ __launch_bounds__(256) void binB_k(const uint* __restrict__ pairs,
                                              const int* __restrict__ gcur,
                                              const int* __restrict__ row_start,
                                              int* __restrict__ csr, int nd) {
    __shared__ int cur[1024];
    int b = blockIdx.x, t = threadIdx.x;
    int dbase = b << 10;
    for (int i = t; i < 1024; i += 256)
        cur[i] = (dbase + i < nd) ? row_start[dbase + i] : 0;
    __syncthreads();
    int ne = gcur[b];
    const uint* bp = pairs + (size_t)b * BCAP;
    for (int i = t; i < ne; i += 256) {
        uint e = bp[i];
        int p = atomicAdd(&cur[e & 1023], 1);
        csr[p] = (int)(e >> 10);
    }
}

// fill pad slots [start+cnt, start+cnt_pad4) with the zero row index
__global__ __launch_bounds__(256) void fill_k(const int* __restrict__ row_start,
                                              const int* __restrict__ cnt,
                                              int* __restrict__ csr, int nd, int zrow) {
    int i = blockIdx.x * blockDim.x + threadIdx.x;
    if (i >= nd) return;
    int s = row_start[i] + cnt[i];
    int e = row_start[i] + ((cnt[i] + 3) & ~3);
    for (int p = s; p < e; ++p) csr[p] = zrow;
}

// ---------- gather4: wave per dst row, 4 independent 256B row loads per iter ----
__global__ __launch_bounds__(256) void gather4_k(const int* __restrict__ csr,
                                                 const int* __restrict__ row_start,
                                                 const int* __restrict__ cnt,
                                                 const ushort* __restrict__ hsrc,
                                                 uint* __restrict__ aggm, int nrows) {
    int w    = (blockIdx.x * blockDim.x + threadIdx.x) >> 6;
    int lane = threadIdx.x & 63;
    if (w >= nrows) return;
    int beg = row_start[w], c = cnt[w];
    int end = beg + ((c + 3) & ~3);
    const uint* hb = (const uint*)hsrc;
    float a0 = 0.f, a1 = 0.f;
    for (int j = beg; j < end; j += 4) {
        int4 s4 = *(const int4*)(csr + j);     // 16B-aligned (rows 4-padded)
        uint u0 = hb[(size_t)s4.x * 64 + lane];
        uint u1 = hb[(size_t)s4.y * 64 + lane];
        uint u2 = hb[(size_t)s4.z * 64 + lane];
        uint u3 = hb[(size_t)s4.w * 64 + lane];
        a0 += (bflo(u0) + bflo(u1)) + (bflo(u2) + bflo(u3));
        a1 += (bfhi(u0) + bfhi(u1)) + (bfhi(u2) + bfhi(u3));
    }
    float inv = 1.0f / fmaxf((float)c, 1.0f);
    aggm[(size_t)w * 64 + lane] = pack2(a0 * inv, a1 * inv);
}

// ---------- W pack: [Ws1;Wn1] (256x256 f32) -> B-fragment-major bf16 ----------
__global__ __launch_bounds__(256) void wconv_k(const float* __restrict__ Ws,
                                               const float* __restrict__ Wn,
                                               uint* __restrict__ Wb) {
    int tid  = blockIdx.x * 256 + threadIdx.x;   // 8192 threads
    int lane = tid & 63, nf = (tid >> 6) & 15, ks = tid >> 10;
    int n  = nf * 16 + (lane & 15);
    int k0 = ks * 32 + ((lane >> 4) << 3);
    uint o[4];
#pragma unroll
    for (int p = 0; p < 4; ++p) {
        int k = k0 + 2 * p;
        float a = (k < 128)     ? Ws[(size_t)k * HF + n]       : Wn[(size_t)(k - 128) * HF + n];
        float b = (k + 1 < 128) ? Ws[(size_t)(k + 1) * HF + n] : Wn[(size_t)(k - 127) * HF + n];
        o[p] = pack2(a, b);
    }
    uint4 v = { o[0], o[1], o[2], o[3] };
    *(uint4*)(Wb + (size_t)tid * 4) = v;
}

// ---------- W pack 2: B2 = [Wn2 (cols 0-7) | Ws2 (cols 8-15)], 256x16 bf16 -----
__global__ __launch_bounds__(256) void wpack2_k(const float* __restrict__ Ws2,
                                                const float* __restrict__ Wn2,
                                                uint* __restrict__ Wb2) {
    int tid = blockIdx.x * 256 + threadIdx.x;   // 512 threads
    if (tid >= 512) return;
    int lane = tid & 63, ks = tid >> 6;
    int n  = lane & 15;
    int k0 = ks * 32 + ((lane >> 4) << 3);
    const float* W = (n < 8) ? Wn2 : Ws2;
    int c = n & 7;
    uint o[4];
#pragma unroll
    for (int p = 0; p < 4; ++p) {
        int k = k0 + 2 * p;
        o[p] = pack2(W[(size_t)k * 8 + c], W[(size_t)(k + 1) * 8 + c]);
    }
    uint4 v = { o[0], o[1], o[2], o[3] };
    *(uint4*)(Wb2 + (size_t)tid * 4) = v;
}

// ---------- layer1 MFMA: h1 = relu([h|aggm] @ Wb + b1), 64x256 tile/block ----------
__global__ __launch_bounds__(256) void layer1_mfma_k(const uint* __restrict__ hb,
                                                     const uint* __restrict__ aggm,
                                                     const uint* __restrict__ Wb,
                                                     const float* __restrict__ b1,
                                                     uint* __restrict__ h1u, int nrows) {
    __shared__ uint lds[64 * 132];   // 33792 B
    int t = threadIdx.x, lane = t & 63, wid = t >> 6;
    int quad = lane >> 4, l16 = lane & 15;
    int r0 = blockIdx.x * 64;

#pragma unroll
    for (int it = 0; it < 8; ++it) {
        int i = t + it * 256;
        int r = i >> 5, u4 = i & 31;
        const uint* src = (u4 < 16) ? (hb + (size_t)(r0 + r) * 64 + u4 * 4)
                                    : (aggm + (size_t)(r0 + r) * 64 + (u4 - 16) * 4);
        *(uint4*)&lds[r * 132 + u4 * 4] = *(const uint4*)src;
    }

    float bias[4];
#pragma unroll
    for (int i = 0; i < 4; ++i) bias[i] = b1[wid * 64 + i * 16 + l16];
    f32x4 acc[4][4];
#pragma unroll
    for (int mf = 0; mf < 4; ++mf)
#pragma unroll
        for (int i = 0; i < 4; ++i)
            acc[mf][i] = (f32x4){ bias[i], bias[i], bias[i], bias[i] };

    __syncthreads();

#pragma unroll
    for (int ks = 0; ks < 8; ++ks) {
        short8 bfr[4];
#pragma unroll
        for (int i = 0; i < 4; ++i) {
            int nf = wid * 4 + i;
            bfr[i] = *(const short8*)(Wb + (size_t)((ks * 16 + nf) * 64 + lane) * 4);
        }
        short8 afr[4];
#pragma unroll
        for (int mf = 0; mf < 4; ++mf) {
            int r = mf * 16 + l16;
            afr[mf] = *(const short8*)&lds[r * 132 + ks * 16 + quad * 4];
        }
#pragma unroll
        for (int mf = 0; mf < 4; ++mf)
#pragma unroll
            for (int i = 0; i < 4; ++i)
                acc[mf][i] = __builtin_amdgcn_mfma_f32_16x16x32_bf16(afr[mf], bfr[i],
                                                                     acc[mf][i], 0, 0, 0);
    }

    __syncthreads();
    ushort* st = (ushort*)lds;
#pragma unroll
    for (int mf = 0; mf < 4; ++mf)
#pragma unroll
        for (int i = 0; i < 4; ++i) {
            int col = wid * 64 + i * 16 + l16;
#pragma unroll
            for (int reg = 0; reg < 4; ++reg) {
                int row = mf * 16 + quad * 4 + reg;
                st[row * 264 + col] = f2bf(fmaxf(acc[mf][i][reg], 0.0f));
            }
        }
    __syncthreads();
#pragma unroll
    for (int it = 0; it < 8; ++it) {
        int i = t + it * 256;
        int r = i >> 5, u4 = i & 31;
        uint4 v = *(uint4*)&lds[r * 132 + u4 * 4];
        *(uint4*)(h1u + (size_t)(r0 + r) * 128 + u4 * 4) = v;
    }
}

// ---------- zs MFMA: one wave = 16 rows x 16 cols; cols 0-7 -> z, 8-15 -> out ----
__global__ __launch_bounds__(256) void zs_mfma_k(const uint* __restrict__ h1u,
                                                 const uint* __restrict__ Wb2,
                                                 float* __restrict__ z,
                                                 float* __restrict__ out,
                                                 int nd0, int nd1) {
    int t = threadIdx.x, lane = t & 63, wid = t >> 6;
    int quad = lane >> 4, l16 = lane & 15;
    int w = blockIdx.x * 4 + wid;
    int r0 = w * 16;
    if (r0 >= nd0) return;

    f32x4 acc = (f32x4){ 0.f, 0.f, 0.f, 0.f };
#pragma unroll
    for (int ks = 0; ks < 8; ++ks) {
        short8 a = *(const short8*)(h1u + (size_t)(r0 + l16) * 128 + ks * 16 + quad * 4);
        short8 b = *(const short8*)(Wb2 + (size_t)(ks * 64 + lane) * 4);
        acc = __builtin_amdgcn_mfma_f32_16x16x32_bf16(a, b, acc, 0, 0, 0);
    }
#pragma unroll
    for (int reg = 0; reg < 4; ++reg) {
        int r = r0 + quad * 4 + reg;
        if (l16 < 8) z[(size_t)r * 8 + l16] = acc[reg];
        else if (r < nd1) out[(size_t)r * 8 + (l16 - 8)] = acc[reg];
    }
}

// ---------- gz: out += mean-gather(z) + b2 ; 8 threads per dst row, unroll 4 ----
__global__ __launch_bounds__(256) void gz_k(const int* __restrict__ csr,
                                            const int* __restrict__ row_start,
                                            const int* __restrict__ cnt,
                                            const float* __restrict__ z,
                                            const float* __restrict__ b2,
                                            float* __restrict__ out, int nrows) {
    int tid = blockIdx.x * 256 + threadIdx.x;
    int d = tid >> 3, c = tid & 7;
    if (d >= nrows) return;
    int beg = row_start[d], n = cnt[d];
    int end = beg + ((n + 3) & ~3);
    float a = 0.f;
    for (int j = beg; j < end; j += 4) {
        int4 s4 = *(const int4*)(csr + j);     // pad slots -> zero z row
        a += z[(size_t)s4.x * 8 + c] + z[(size_t)s4.y * 8 + c]
           + z[(size_t)s4.z * 8 + c] + z[(size_t)s4.w * 8 + c];
    }
    float inv = 1.0f / fmaxf((float)n, 1.0f);
    out[(size_t)d * 8 + c] += a * inv + b2[c];
}

extern "C" void kernel_launch(void* const* d_in, const int* in_sizes, int n_in,
                              void* d_out, int out_size, void* d_ws, size_t ws_size,
                              hipStream_t stream) {
    const float* x    = (const float*)d_in[0];
    const int*   src0 = (const int*)d_in[1];
    const int*   dst0 = (const int*)d_in[2];
    const int*   src1 = (const int*)d_in[3];
    const int*   dst1 = (const int*)d_in[4];
    const float* emb  = (const float*)d_in[7];
    const float* Ws1  = (const float*)d_in[8];
    const float* Wn1  = (const float*)d_in[9];
    const float* b1   = (const float*)d_in[10];
    const float* Ws2  = (const float*)d_in[11];
    const float* Wn2  = (const float*)d_in[12];
    const float* b2   = (const float*)d_in[13];
    int E0 = in_sizes[1];
    int E1 = in_sizes[3];
    int nsrc = in_sizes[0] / 129;   // 400000

    // ---- workspace layout ----
    char* p = (char*)d_ws;
    ushort* h         = (ushort*)p;  p += ((size_t)nsrc + 1) * INF * 2;  // +1 zero row
    ushort* h1        = (ushort*)p;  p += (size_t)ND0 * HF * 2;
    uint*   aggm      = (uint*)p;    p += (size_t)ND0 * 64 * 4;          // 51.2 MB
    int*    csr       = (int*)p;     p += ((size_t)E0 + 3 * (size_t)ND0 + 16) * 4;
    int*    cnt       = (int*)p;     p += (size_t)ND0 * 4;
    int*    row_start = (int*)p;     p += (size_t)ND0 * 4;
    int*    bsum      = (int*)p;     p += 256 * 4;
    int*    gcur      = (int*)p;     p += 256 * 4;
    uint*   Wb        = (uint*)p;    p += 8192 * 16;
    uint*   Wb2       = (uint*)p;    p += 512 * 16;                      // 8 KB
    float*  z         = (float*)p;   p += ((size_t)ND0 + 1) * 8 * 4;     // +1 zero row
    // pairs overlaid on aggm (dead during CSR build; stream order makes it safe)
    uint*   pairs     = aggm;        // 256*BCAP*4 = 25.2 MB <= 51.2 MB

    int ZR0 = nsrc;   // zero row index in h
    int ZR1 = ND0;    // zero row index in z

    // ---- layer 0/1 ----
    hipMemsetAsync(cnt, 0, (size_t)ND0 * 4, stream);
    hipMemsetAsync(gcur, 0, 256 * 4, stream);
    hipMemsetAsync(h + (size_t)ZR0 * INF, 0, INF * 2, stream);
    gate_k<<<(nsrc * 16 + 255) / 256, 256, 0, stream>>>(x, emb, h, nsrc);
    wconv_k<<<32, 256, 0, stream>>>(Ws1, Wn1, Wb);
    wpack2_k<<<2, 256, 0, stream>>>(Ws2, Wn2, Wb2);
    hist_k<<<(E0 + 255) / 256, 256, 0, stream>>>(dst0, cnt, E0);
    int nb0 = (ND0 + SCAN_B - 1) / SCAN_B;   // 196
    scan1_k<<<nb0, 256, 0, stream>>>(cnt, row_start, bsum, ND0);
    scan2_k<<<1, 256, 0, stream>>>(bsum, nb0);
    scan3_k<<<(ND0 + 255) / 256, 256, 0, stream>>>(row_start, bsum, ND0);
    binA_k<<<512, 256, 0, stream>>>(src0, dst0, pairs, gcur, E0);
    binB_k<<<nb0, 256, 0, stream>>>(pairs, gcur, row_start, csr, ND0);
    fill_k<<<(ND0 + 255) / 256, 256, 0, stream>>>(row_start, cnt, csr, ND0, ZR0);
    gather4_k<<<(ND0 + 3) / 4, 256, 0, stream>>>(csr, row_start, cnt, h, aggm, ND0);
    layer1_mfma_k<<<ND0 / 64, 256, 0, stream>>>((const uint*)h, aggm, Wb, b1,
                                                (uint*)h1, ND0);

    // ---- layer 2 ----
    hipMemsetAsync(cnt, 0, (size_t)ND1 * 4, stream);
    hipMemsetAsync(gcur, 0, 256 * 4, stream);
    hipMemsetAsync(z + (size_t)ZR1 * 8, 0, 8 * 4, stream);
    hist_k<<<(E1 + 255) / 256, 256, 0, stream>>>(dst1, cnt, E1);
    int nb1 = (ND1 + SCAN_B - 1) / SCAN_B;   // 98
    scan1_k<<<nb1, 256, 0, stream>>>(cnt, row_start, bsum, ND1);
    scan2_k<<<1, 256, 0, stream>>>(bsum, nb1);
    scan3_k<<<(ND1 + 255) / 256, 256, 0, stream>>>(row_start, bsum, ND1);
    binA_k<<<512, 256, 0, stream>>>(src1, dst1, pairs, gcur, E1);
    binB_k<<<nb1, 256, 0, stream>>>(pairs, gcur, row_start, csr, ND1);
    fill_k<<<(ND1 + 255) / 256, 256, 0, stream>>>(row_start, cnt, csr, ND1, ZR1);
    zs_mfma_k<<<(ND0 / 16 + 3) / 4, 256, 0, stream>>>((const uint*)h1, Wb2, z,
                                                      (float*)d_out, ND0, ND1);
    gz_k<<<(ND1 * 8 + 255) / 256, 256, 0, stream>>>(csr, row_start, cnt, z, b2,
                                                    (float*)d_out, ND1);
}

// Round 9
// 876.831 us; speedup vs baseline: 7.6563x; 1.0693x over previous
//
#include <hip/hip_runtime.h>

typedef unsigned int uint;
typedef unsigned short ushort;
typedef __attribute__((ext_vector_type(8))) short short8;   // 8 bf16 (4 VGPRs)
typedef __attribute__((ext_vector_type(4))) float f32x4;    // MFMA accumulator

// ---------- bf16 helpers (internal storage only; I/O is fp32) ----------
__device__ __forceinline__ float bflo(uint u) { return __uint_as_float(u << 16); }
__device__ __forceinline__ float bfhi(uint u) { return __uint_as_float(u & 0xffff0000u); }
__device__ __forceinline__ ushort f2bf(float f) {
    uint u = __float_as_uint(f);
    u += 0x7fffu + ((u >> 16) & 1u);   // round-to-nearest-even
    return (ushort)(u >> 16);
}
__device__ __forceinline__ uint pack2(float a, float b) {
    return (uint)f2bf(a) | ((uint)f2bf(b) << 16);
}
__device__ __forceinline__ float sigm(float e) { return 1.0f / (1.0f + __expf(-e)); }

#define ND0 200000
#define ND1 100000
#define INF 128
#define HF  256
#define BCAP 24576   // max edges per 1024-dst bucket (mean ~16.3k)

// ---------- 1) gate: h[n,f] = feat * sigmoid(emb[cell_id]) ; h bf16 ----------
__global__ __launch_bounds__(256) void gate_k(const float* __restrict__ x,
                                              const float* __restrict__ emb,
                                              ushort* __restrict__ h, int nnodes) {
    int tid  = blockIdx.x * 256 + threadIdx.x;
    int node = tid >> 4, tq = tid & 15;
    if (node >= nnodes) return;
    const float* xr = x + (size_t)node * 129;
    int cell = (int)xr[0];
    int f0 = tq * 8;
    const float* er = emb + cell * INF + f0;
    float4 e0 = *(const float4*)er;
    float4 e1 = *(const float4*)(er + 4);
    float v[8];
    __builtin_memcpy(&v[0], xr + 1 + f0, 16);      // 4B-aligned dwordx4
    __builtin_memcpy(&v[4], xr + 5 + f0, 16);
    uint4 o;
    o.x = pack2(v[0] * sigm(e0.x), v[1] * sigm(e0.y));
    o.y = pack2(v[2] * sigm(e0.z), v[3] * sigm(e0.w));
    o.z = pack2(v[4] * sigm(e1.x), v[5] * sigm(e1.y));
    o.w = pack2(v[6] * sigm(e1.z), v[7] * sigm(e1.w));
    *(uint4*)(h + (size_t)node * INF + f0) = o;
}

// ---------- CSR build ----------
#define SCAN_B 1024
// scans PADDED counts: (cnt+3)&~3 — keeps every CSR row 4-aligned
__global__ __launch_bounds__(256) void scan1_k(const int* __restrict__ in,
                                               int* __restrict__ out,
                                               int* __restrict__ bsum, int n) {
    __shared__ int tmp[256];
    int t = threadIdx.x;
    int base = blockIdx.x * SCAN_B;
    int v[4], s = 0;
#pragma unroll
    for (int q = 0; q < 4; ++q) {
        int idx = base + t * 4 + q;
        v[q] = (idx < n) ? ((in[idx] + 3) & ~3) : 0;
        s += v[q];
    }
    tmp[t] = s; __syncthreads();
    for (int off = 1; off < 256; off <<= 1) {
        int xv = (t >= off) ? tmp[t - off] : 0; __syncthreads();
        tmp[t] += xv; __syncthreads();
    }
    int excl = tmp[t] - s;
#pragma unroll
    for (int q = 0; q < 4; ++q) {
        int idx = base + t * 4 + q;
        if (idx < n) out[idx] = excl;
        excl += v[q];
    }
    if (t == 255) bsum[blockIdx.x] = tmp[255];
}

__global__ __launch_bounds__(256) void scan2_k(int* __restrict__ bsum, int nb) {
    __shared__ int tmp[256];
    int t = threadIdx.x;
    int s = (t < nb) ? bsum[t] : 0;
    tmp[t] = s; __syncthreads();
    for (int off = 1; off < 256; off <<= 1) {
        int xv = (t >= off) ? tmp[t - off] : 0; __syncthreads();
        tmp[t] += xv; __syncthreads();
    }
    if (t < nb) bsum[t] = tmp[t] - s;   // exclusive
}

__global__ __launch_bounds__(256) void scan3_k(int* __restrict__ row_start,
                                               const int* __restrict__ bsum, int n) {
    int i = blockIdx.x * blockDim.x + threadIdx.x;
    if (i < n) row_start[i] += bsum[i >> 10];
}

// binA: partition edges into 1024-wide dst buckets + per-dst histogram (fused hist)
__global__ __launch_bounds__(256) void binA_k(const int* __restrict__ src,
                                              const int* __restrict__ dst,
                                              uint* __restrict__ pairs,
                                              int* __restrict__ gcur,
                                              int* __restrict__ cnt, int E) {
    __shared__ int hist[256];
    __shared__ int curs[256];
    const int CHUNK = 4096;
    int t = threadIdx.x;
    for (int c0 = blockIdx.x * CHUNK; c0 < E; c0 += gridDim.x * CHUNK) {
        int n = min(CHUNK, E - c0);
        hist[t] = 0;
        __syncthreads();
        for (int i = t; i < n; i += 256) atomicAdd(&hist[dst[c0 + i] >> 10], 1);
        __syncthreads();
        curs[t] = hist[t] ? atomicAdd(&gcur[t], hist[t]) : 0;
        __syncthreads();
        for (int i = t; i < n; i += 256) {
            int d = dst[c0 + i];
            atomicAdd(&cnt[d], 1);            // fused per-dst histogram (L2-resident)
            int b = d >> 10;
            int p = atomicAdd(&curs[b], 1);
            pairs[(size_t)b * BCAP + p] = ((uint)src[c0 + i] << 10) | (uint)(d & 1023);
        }
        __syncthreads();
    }
}

// binB: one block per bucket, LDS per-dst cursors, L2-local csr writes + pad fill
__global__ __launch_bounds__(256) void binB_k(const uint* __restrict__ pairs,
                                              const int* __restrict__ gcur,
                                              const int* __restrict__ row_start,
                                              int* __restrict__ csr, int nd, int zrow) {
    __shared__ int cur[1024];
    int b = blockIdx.x, t = threadIdx.x;
    int dbase = b << 10;
    for (int i = t; i < 1024; i += 256)
        cur[i] = (dbase + i < nd) ? row_start[dbase + i] : 0;
    __syncthreads();
    int ne = gcur[b];
    const uint* bp = pairs + (size_t)b * BCAP;
    for (int i = t; i < ne; i += 256) {
        uint e = bp[i];
        int p = atomicAdd(&cur[e & 1023], 1);
        csr[p] = (int)(e >> 10);
    }
    __syncthreads();
    // pad each row to a multiple of 4 with the zero-row index (fused fill)
    for (int i = t; i < 1024; i += 256) {
        if (dbase + i >= nd) continue;
        int pe = cur[i];                       // row_start + cnt
        int pad = (-(pe - row_start[dbase + i])) & 3;
        for (int q = 0; q < pad; ++q) csr[pe + q] = zrow;
    }
}

// ---------- gather4: wave per dst row, 4 independent 256B row loads per iter ----
__global__ __launch_bounds__(256) void gather4_k(const int* __restrict__ csr,
                                                 const int* __restrict__ row_start,
                                                 const int* __restrict__ cnt,
                                                 const ushort* __restrict__ hsrc,
                                                 uint* __restrict__ aggm, int nrows) {
    int w    = (blockIdx.x * blockDim.x + threadIdx.x) >> 6;
    int lane = threadIdx.x & 63;
    if (w >= nrows) return;
    int beg = row_start[w], c = cnt[w];
    int end = beg + ((c + 3) & ~3);
    const uint* hb = (const uint*)hsrc;
    float a0 = 0.f, a1 = 0.f;
    for (int j = beg; j < end; j += 4) {
        int4 s4 = *(const int4*)(csr + j);     // 16B-aligned (rows 4-padded)
        uint u0 = hb[(size_t)s4.x * 64 + lane];
        uint u1 = hb[(size_t)s4.y * 64 + lane];
        uint u2 = hb[(size_t)s4.z * 64 + lane];
        uint u3 = hb[(size_t)s4.w * 64 + lane];
        a0 += (bflo(u0) + bflo(u1)) + (bflo(u2) + bflo(u3));
        a1 += (bfhi(u0) + bfhi(u1)) + (bfhi(u2) + bfhi(u3));
    }
    float inv = 1.0f / fmaxf((float)c, 1.0f);
    aggm[(size_t)w * 64 + lane] = pack2(a0 * inv, a1 * inv);
}

// ---------- W pack: [Ws1;Wn1] (256x256 f32) -> B-fragment-major bf16 ----------
__global__ __launch_bounds__(256) void wconv_k(const float* __restrict__ Ws,
                                               const float* __restrict__ Wn,
                                               uint* __restrict__ Wb) {
    int tid  = blockIdx.x * 256 + threadIdx.x;   // 8192 threads
    int lane = tid & 63, nf = (tid >> 6) & 15, ks = tid >> 10;
    int n  = nf * 16 + (lane & 15);
    int k0 = ks * 32 + ((lane >> 4) << 3);
    uint o[4];
#pragma unroll
    for (int p = 0; p < 4; ++p) {
        int k = k0 + 2 * p;
        float a = (k < 128)     ? Ws[(size_t)k * HF + n]       : Wn[(size_t)(k - 128) * HF + n];
        float b = (k + 1 < 128) ? Ws[(size_t)(k + 1) * HF + n] : Wn[(size_t)(k - 127) * HF + n];
        o[p] = pack2(a, b);
    }
    uint4 v = { o[0], o[1], o[2], o[3] };
    *(uint4*)(Wb + (size_t)tid * 4) = v;
}

// ---------- W pack 2: B2 = [Wn2 (cols 0-7) | Ws2 (cols 8-15)], 256x16 bf16 -----
__global__ __launch_bounds__(256) void wpack2_k(const float* __restrict__ Ws2,
                                                const float* __restrict__ Wn2,
                                                uint* __restrict__ Wb2) {
    int tid = blockIdx.x * 256 + threadIdx.x;   // 512 threads
    if (tid >= 512) return;
    int lane = tid & 63, ks = tid >> 6;
    int n  = lane & 15;
    int k0 = ks * 32 + ((lane >> 4) << 3);
    const float* W = (n < 8) ? Wn2 : Ws2;
    int c = n & 7;
    uint o[4];
#pragma unroll
    for (int p = 0; p < 4; ++p) {
        int k = k0 + 2 * p;
        o[p] = pack2(W[(size_t)k * 8 + c], W[(size_t)(k + 1) * 8 + c]);
    }
    uint4 v = { o[0], o[1], o[2], o[3] };
    *(uint4*)(Wb2 + (size_t)tid * 4) = v;
}

// ---------- layer1+zs fused: h1_tile = relu([h|aggm]@Wb + b1) in LDS, then ------
// z = h1@Wn2 and out_self = h1@Ws2 via 8 more MFMAs. h1 never touches global.
__global__ __launch_bounds__(256) void layer1_mfma_k(const uint* __restrict__ hb,
                                                     const uint* __restrict__ aggm,
                                                     const uint* __restrict__ Wb,
                                                     const uint* __restrict__ Wb2,
                                                     const float* __restrict__ b1,
                                                     float* __restrict__ z,
                                                     float* __restrict__ out, int nd1) {
    __shared__ uint lds[64 * 132];   // 33792 B
    int t = threadIdx.x, lane = t & 63, wid = t >> 6;
    int quad = lane >> 4, l16 = lane & 15;
    int r0 = blockIdx.x * 64;

#pragma unroll
    for (int it = 0; it < 8; ++it) {
        int i = t + it * 256;
        int r = i >> 5, u4 = i & 31;
        const uint* src = (u4 < 16) ? (hb + (size_t)(r0 + r) * 64 + u4 * 4)
                                    : (aggm + (size_t)(r0 + r) * 64 + (u4 - 16) * 4);
        *(uint4*)&lds[r * 132 + u4 * 4] = *(const uint4*)src;
    }

    float bias[4];
#pragma unroll
    for (int i = 0; i < 4; ++i) bias[i] = b1[wid * 64 + i * 16 + l16];
    f32x4 acc[4][4];
#pragma unroll
    for (int mf = 0; mf < 4; ++mf)
#pragma unroll
        for (int i = 0; i < 4; ++i)
            acc[mf][i] = (f32x4){ bias[i], bias[i], bias[i], bias[i] };

    __syncthreads();

#pragma unroll
    for (int ks = 0; ks < 8; ++ks) {
        short8 bfr[4];
#pragma unroll
        for (int i = 0; i < 4; ++i) {
            int nf = wid * 4 + i;
            bfr[i] = *(const short8*)(Wb + (size_t)((ks * 16 + nf) * 64 + lane) * 4);
        }
        short8 afr[4];
#pragma unroll
        for (int mf = 0; mf < 4; ++mf) {
            int r = mf * 16 + l16;
            afr[mf] = *(const short8*)&lds[r * 132 + ks * 16 + quad * 4];
        }
#pragma unroll
        for (int mf = 0; mf < 4; ++mf)
#pragma unroll
            for (int i = 0; i < 4; ++i)
                acc[mf][i] = __builtin_amdgcn_mfma_f32_16x16x32_bf16(afr[mf], bfr[i],
                                                                     acc[mf][i], 0, 0, 0);
    }

    __syncthreads();
    // epilogue: relu -> bf16 h1 tile in LDS (ushort stride 264 == dword 132)
    ushort* st = (ushort*)lds;
#pragma unroll
    for (int mf = 0; mf < 4; ++mf)
#pragma unroll
        for (int i = 0; i < 4; ++i) {
            int col = wid * 64 + i * 16 + l16;
#pragma unroll
            for (int reg = 0; reg < 4; ++reg) {
                int row = mf * 16 + quad * 4 + reg;
                st[row * 264 + col] = f2bf(fmaxf(acc[mf][i][reg], 0.0f));
            }
        }
    __syncthreads();

    // fused zs: wave wid handles local rows wid*16..wid*16+15 (K=256 from LDS)
    f32x4 zacc = (f32x4){ 0.f, 0.f, 0.f, 0.f };
    int rloc = wid * 16 + l16;
#pragma unroll
    for (int ks = 0; ks < 8; ++ks) {
        short8 a = *(const short8*)&lds[rloc * 132 + ks * 16 + quad * 4];
        short8 b = *(const short8*)(Wb2 + (size_t)(ks * 64 + lane) * 4);
        zacc = __builtin_amdgcn_mfma_f32_16x16x32_bf16(a, b, zacc, 0, 0, 0);
    }
#pragma unroll
    for (int reg = 0; reg < 4; ++reg) {
        int r = r0 + wid * 16 + quad * 4 + reg;
        if (l16 < 8) z[(size_t)r * 8 + l16] = zacc[reg];
        else if (r < nd1) out[(size_t)r * 8 + (l16 - 8)] = zacc[reg];
    }
}

// ---------- gz: out += mean-gather(z) + b2 ; 8 threads per dst row, unroll 4 ----
__global__ __launch_bounds__(256) void gz_k(const int* __restrict__ csr,
                                            const int* __restrict__ row_start,
                                            const int* __restrict__ cnt,
                                            const float* __restrict__ z,
                                            const float* __restrict__ b2,
                                            float* __restrict__ out, int nrows) {
    int tid = blockIdx.x * 256 + threadIdx.x;
    int d = tid >> 3, c = tid & 7;
    if (d >= nrows) return;
    int beg = row_start[d], n = cnt[d];
    int end = beg + ((n + 3) & ~3);
    float a = 0.f;
    for (int j = beg; j < end; j += 4) {
        int4 s4 = *(const int4*)(csr + j);     // pad slots -> zero z row
        a += z[(size_t)s4.x * 8 + c] + z[(size_t)s4.y * 8 + c]
           + z[(size_t)s4.z * 8 + c] + z[(size_t)s4.w * 8 + c];
    }
    float inv = 1.0f / fmaxf((float)n, 1.0f);
    out[(size_t)d * 8 + c] += a * inv + b2[c];
}

extern "C" void kernel_launch(void* const* d_in, const int* in_sizes, int n_in,
                              void* d_out, int out_size, void* d_ws, size_t ws_size,
                              hipStream_t stream) {
    const float* x    = (const float*)d_in[0];
    const int*   src0 = (const int*)d_in[1];
    const int*   dst0 = (const int*)d_in[2];
    const int*   src1 = (const int*)d_in[3];
    const int*   dst1 = (const int*)d_in[4];
    const float* emb  = (const float*)d_in[7];
    const float* Ws1  = (const float*)d_in[8];
    const float* Wn1  = (const float*)d_in[9];
    const float* b1   = (const float*)d_in[10];
    const float* Ws2  = (const float*)d_in[11];
    const float* Wn2  = (const float*)d_in[12];
    const float* b2   = (const float*)d_in[13];
    int E0 = in_sizes[1];
    int E1 = in_sizes[3];
    int nsrc = in_sizes[0] / 129;   // 400000

    // ---- workspace layout ----
    char* p = (char*)d_ws;
    ushort* h         = (ushort*)p;  p += ((size_t)nsrc + 1) * INF * 2;  // +1 zero row
    uint*   aggm      = (uint*)p;    p += (size_t)ND0 * 64 * 4;          // 51.2 MB
    int*    csr       = (int*)p;     p += ((size_t)E0 + 3 * (size_t)ND0 + 16) * 4;
    int*    cnt       = (int*)p;     p += (size_t)ND0 * 4;
    int*    row_start = (int*)p;     p += (size_t)ND0 * 4;
    int*    bsum      = (int*)p;     p += 256 * 4;
    int*    gcur      = (int*)p;     p += 256 * 4;
    uint*   Wb        = (uint*)p;    p += 8192 * 16;
    uint*   Wb2       = (uint*)p;    p += 512 * 16;                      // 8 KB
    float*  z         = (float*)p;   p += ((size_t)ND0 + 1) * 8 * 4;     // +1 zero row
    // pairs overlaid on aggm (dead during CSR build; stream order makes it safe)
    uint*   pairs     = aggm;        // 256*BCAP*4 = 25.2 MB <= 51.2 MB

    int ZR0 = nsrc;   // zero row index in h
    int ZR1 = ND0;    // zero row index in z

    // ---- layer 0/1 ----
    hipMemsetAsync(cnt, 0, (size_t)ND0 * 4, stream);
    hipMemsetAsync(gcur, 0, 256 * 4, stream);
    hipMemsetAsync(h + (size_t)ZR0 * INF, 0, INF * 2, stream);
    gate_k<<<(nsrc * 16 + 255) / 256, 256, 0, stream>>>(x, emb, h, nsrc);
    wconv_k<<<32, 256, 0, stream>>>(Ws1, Wn1, Wb);
    wpack2_k<<<2, 256, 0, stream>>>(Ws2, Wn2, Wb2);
    int nb0 = (ND0 + SCAN_B - 1) / SCAN_B;   // 196
    binA_k<<<512, 256, 0, stream>>>(src0, dst0, pairs, gcur, cnt, E0);
    scan1_k<<<nb0, 256, 0, stream>>>(cnt, row_start, bsum, ND0);
    scan2_k<<<1, 256, 0, stream>>>(bsum, nb0);
    scan3_k<<<(ND0 + 255) / 256, 256, 0, stream>>>(row_start, bsum, ND0);
    binB_k<<<nb0, 256, 0, stream>>>(pairs, gcur, row_start, csr, ND0, ZR0);
    gather4_k<<<(ND0 + 3) / 4, 256, 0, stream>>>(csr, row_start, cnt, h, aggm, ND0);
    layer1_mfma_k<<<ND0 / 64, 256, 0, stream>>>((const uint*)h, aggm, Wb, Wb2, b1,
                                                z, (float*)d_out, ND1);

    // ---- layer 2 CSR + neighbor head (z already computed by fused layer1) ----
    hipMemsetAsync(cnt, 0, (size_t)ND1 * 4, stream);
    hipMemsetAsync(gcur, 0, 256 * 4, stream);
    hipMemsetAsync(z + (size_t)ZR1 * 8, 0, 8 * 4, stream);
    int nb1 = (ND1 + SCAN_B - 1) / SCAN_B;   // 98
    binA_k<<<512, 256, 0, stream>>>(src1, dst1, pairs, gcur, cnt, E1);
    scan1_k<<<nb1, 256, 0, stream>>>(cnt, row_start, bsum, ND1);
    scan2_k<<<1, 256, 0, stream>>>(bsum, nb1);
    scan3_k<<<(ND1 + 255) / 256, 256, 0, stream>>>(row_start, bsum, ND1);
    binB_k<<<nb1, 256, 0, stream>>>(pairs, gcur, row_start, csr, ND1, ZR1);
    gz_k<<<(ND1 * 8 + 255) / 256, 256, 0, stream>>>(csr, row_start, cnt, z, b2,
                                                    (float*)d_out, ND1);
}